// Round 14
// baseline (2415.554 us; speedup 1.0000x reference)
//
#include <hip/hip_runtime.h>
#include <cmath>

#define DEV __device__ __forceinline__

// ---------- constants ----------
// B=16, T=96, K=64, D=768, H=400, L=3, M=500
// BT = 1536, 4H = 1600, both dirs = 3200, 2H = 800
// NOTE: the LSTM stack is chaotic (||Whh||~6): recurrence must be fp32-exact
// (fp16 W failed, r2). fp32 k-split reassociation is safe (r8/r12 passed).
// Sync history: r4 counter barrier ~14us/step; r5 threadfence = L2 walks;
// r6 fence-free agent atomics WIN; r10 optimistic sentinel loads REGRESSED.
// LESSON: flag-then-load, loads issued exactly once.
// Dot history: r7 4-way k-split bank-perfect; r8 8-way contiguous aliased;
// r11 W-in-registers spilled; r12 half-split WIN 545->407; r13 quarter-split
// WIN 407->388 (400 blk = dir x quarter x 50 slices, 32 rows x 4 bats).
// r14: sync streamline — 4 barriers/step -> 2. All publishers are wave0
// lanes 0-31, so wave-local s_waitcnt vmcnt(0) replaces the block drain
// barrier before the flag; each thread polls ONLY the 3-4 flags guarding
// its own h-loads (slice=jj/8) and loads immediately after each passes.
// Also: MLP 1536x500 GEMMs back to 64x64 tiles (192 blocks vs 48).

#define NBLK_LSTM 400

DEV float wred_max(float v){ for(int o=32;o;o>>=1) v=fmaxf(v,__shfl_xor(v,o)); return v; }
DEV float wred_sum(float v){ for(int o=32;o;o>>=1) v+=__shfl_xor(v,o); return v; }
DEV float sigf(float x){ return 1.f/(1.f+__expf(-x)); }

DEV float agent_ld(const float* p){
  return __hip_atomic_load(p, __ATOMIC_RELAXED, __HIP_MEMORY_SCOPE_AGENT);
}
DEV void agent_st(float* p, float v){
  __hip_atomic_store(p, v, __ATOMIC_RELAXED, __HIP_MEMORY_SCOPE_AGENT);
}
DEV unsigned flag_ld(const unsigned* p){
  return __hip_atomic_load(p, __ATOMIC_RELAXED, __HIP_MEMORY_SCOPE_AGENT);
}

// ---------- embedding gather ----------
__global__ __launch_bounds__(256) void embed_kern(const float* __restrict__ tab,
                                                  const int* __restrict__ labels,
                                                  float* __restrict__ x0){
  long idx = (long)blockIdx.x*256 + threadIdx.x;   // BT*768
  if (idx >= 1536L*768) return;
  int m = (int)(idx/768), d = (int)(idx%768);
  x0[idx] = tab[(long)labels[m]*768 + d];
}

// ---------- transpose biaffine 500x500 ----------
__global__ __launch_bounds__(256) void trans_sq(const float* __restrict__ w,
                                                float* __restrict__ wt){
  int idx = blockIdx.x*256 + threadIdx.x;          // 250,000
  if (idx >= 250000) return;
  int j = idx/500, i = idx%500;
  wt[idx] = w[(long)i*500 + j];                    // wt[j][i] = w[i][j]
}

// ---------- 64x64 fp32 GEMM ----------
__global__ __launch_bounds__(256) void gemm_abt(const float* __restrict__ A,
                                                const float* __restrict__ Bm,
                                                float* __restrict__ C,
                                                const float* __restrict__ bias,
                                                int M, int N, int K,
                                                long sA, long sB, long sC, int leaky){
  A  += (long)blockIdx.z * sA;
  Bm += (long)blockIdx.z * sB;
  C  += (long)blockIdx.z * sC;
  __shared__ float As[16][68];
  __shared__ float Bs[16][68];
  int tid = threadIdx.x;
  int tx = tid & 15, ty = tid >> 4;
  int m0 = blockIdx.x * 64, n0 = blockIdx.y * 64;
  int lrow = tid >> 2, lc = (tid & 3) * 4;
  float acc[4][4] = {};
  for (int k0 = 0; k0 < K; k0 += 16) {
    #pragma unroll
    for (int u = 0; u < 4; u++) {
      int k = k0 + lc + u;
      int am = m0 + lrow;
      As[lc+u][lrow] = (am < M && k < K) ? A[(long)am*K + k] : 0.f;
      int bn = n0 + lrow;
      Bs[lc+u][lrow] = (bn < N && k < K) ? Bm[(long)bn*K + k] : 0.f;
    }
    __syncthreads();
    #pragma unroll
    for (int kk = 0; kk < 16; kk++) {
      float a[4], bb[4];
      #pragma unroll
      for (int u=0;u<4;u++){ a[u]=As[kk][ty*4+u]; bb[u]=Bs[kk][tx*4+u]; }
      #pragma unroll
      for (int i=0;i<4;i++)
        #pragma unroll
        for (int j=0;j<4;j++) acc[i][j] = fmaf(a[i], bb[j], acc[i][j]);
    }
    __syncthreads();
  }
  #pragma unroll
  for (int i=0;i<4;i++){
    int m = m0 + ty*4 + i;
    if (m >= M) continue;
    #pragma unroll
    for (int j=0;j<4;j++){
      int n = n0 + tx*4 + j;
      if (n >= N) continue;
      float v = acc[i][j];
      if (bias) v += bias[n];
      if (leaky) v = v > 0.f ? v : 0.1f*v;
      C[(long)m*N + n] = v;
    }
  }
}

// ---------- 128x128 fp32 GEMM: C[m,n] = sum_k A[m,k]*B[n,k] (+bias,leaky) ----
__global__ __launch_bounds__(256) void gemm128(const float* __restrict__ A,
                                               const float* __restrict__ Bm,
                                               float* __restrict__ C,
                                               const float* __restrict__ bias,
                                               int M, int N, int K, int leaky){
  __shared__ float As[16][132];
  __shared__ float Bs[16][132];
  int tid = threadIdx.x;
  int tx = tid & 15, ty = tid >> 4;
  int m0 = blockIdx.x*128, n0 = blockIdx.y*128;
  int lr = tid >> 1, lq = (tid & 1)*8;
  const float* Arow = A + (size_t)(m0+lr)*K + lq;
  const float* Brow = Bm + (size_t)(n0+lr)*K + lq;
  bool bok = (n0 + lr) < N;
  float acc[8][8] = {};
  for (int k0 = 0; k0 < K; k0 += 16){
    if (k0 + 16 <= K){
      float4 a0 = *(const float4*)(Arow + k0);
      float4 a1 = *(const float4*)(Arow + k0 + 4);
      float4 b0 = {0,0,0,0}, b1 = {0,0,0,0};
      if (bok){ b0 = *(const float4*)(Brow + k0); b1 = *(const float4*)(Brow + k0 + 4); }
      As[lq+0][lr]=a0.x; As[lq+1][lr]=a0.y; As[lq+2][lr]=a0.z; As[lq+3][lr]=a0.w;
      As[lq+4][lr]=a1.x; As[lq+5][lr]=a1.y; As[lq+6][lr]=a1.z; As[lq+7][lr]=a1.w;
      Bs[lq+0][lr]=b0.x; Bs[lq+1][lr]=b0.y; Bs[lq+2][lr]=b0.z; Bs[lq+3][lr]=b0.w;
      Bs[lq+4][lr]=b1.x; Bs[lq+5][lr]=b1.y; Bs[lq+6][lr]=b1.z; Bs[lq+7][lr]=b1.w;
    } else {
      #pragma unroll
      for (int u = 0; u < 8; u++){
        int k = k0 + lq + u;
        As[lq+u][lr] = (k < K) ? Arow[k0+u] : 0.f;
        Bs[lq+u][lr] = (bok && k < K) ? Brow[k0+u] : 0.f;
      }
    }
    __syncthreads();
    #pragma unroll
    for (int kk = 0; kk < 16; kk++){
      float4 a0 = *(const float4*)&As[kk][ty*8];
      float4 a1 = *(const float4*)&As[kk][ty*8+4];
      float4 b0 = *(const float4*)&Bs[kk][tx*8];
      float4 b1 = *(const float4*)&Bs[kk][tx*8+4];
      float av[8] = {a0.x,a0.y,a0.z,a0.w,a1.x,a1.y,a1.z,a1.w};
      float bv[8] = {b0.x,b0.y,b0.z,b0.w,b1.x,b1.y,b1.z,b1.w};
      #pragma unroll
      for (int i=0;i<8;i++)
        #pragma unroll
        for (int j=0;j<8;j++) acc[i][j] = fmaf(av[i], bv[j], acc[i][j]);
    }
    __syncthreads();
  }
  bool full = (n0 + 128 <= N);
  #pragma unroll
  for (int i = 0; i < 8; i++){
    int m = m0 + ty*8 + i;
    float* Crow = C + (size_t)m*N;
    if (full){
      float4 v0, v1;
      float* p0 = &v0.x; float* p1 = &v1.x;
      #pragma unroll
      for (int j = 0; j < 4; j++){
        int n = n0 + tx*8 + j;
        float v = acc[i][j];
        if (bias) v += bias[n];
        if (leaky) v = v > 0.f ? v : 0.1f*v;
        p0[j] = v;
      }
      #pragma unroll
      for (int j = 4; j < 8; j++){
        int n = n0 + tx*8 + j;
        float v = acc[i][j];
        if (bias) v += bias[n];
        if (leaky) v = v > 0.f ? v : 0.1f*v;
        p1[j-4] = v;
      }
      *(float4*)(Crow + n0 + tx*8)     = v0;
      *(float4*)(Crow + n0 + tx*8 + 4) = v1;
    } else {
      #pragma unroll
      for (int j = 0; j < 8; j++){
        int n = n0 + tx*8 + j;
        if (n < N){
          float v = acc[i][j];
          if (bias) v += bias[n];
          if (leaky) v = v > 0.f ? v : 0.1f*v;
          Crow[n] = v;
        }
      }
    }
  }
}

// ---------- weight-stationary grid-synced LSTM (one layer, 96 steps) --------
// r13 decomposition + r14 sync streamline. 400 blocks = dir(2) x quarter(4)
// x slice(50); block = 32 W-rows x 4 bats; dot: ks=(tid>>2)&15 interleaved,
// rowg=(tid&3)|((tid>>6)<<2). Per step only TWO barriers:
//   dot -> sync(A) -> [wave0 lanes<32: epilogue+publish] -> wave0:
//   s_waitcnt vmcnt(0); lane0 raises flag -> every thread polls only the
//   3-4 flags guarding ITS h-loads (slice=jj/8) and loads right after each
//   passes (exactly-once loads) -> commit hl -> sync(B).
// Deadlock-free: flag raise precedes all polls in program order per block.
// Parity-lifetime proof: flag(s+1) implies step-s loads done (sync(B)
// precedes the step-s+1 dot and flag), so parity reuse at s+2 is safe.
__global__ __launch_bounds__(128) void lstm_grid(const float* __restrict__ G,
                                                 const float* __restrict__ whh,
                                                 float* __restrict__ xout,
                                                 float* __restrict__ hbufG,
                                                 unsigned* __restrict__ flags,
                                                 int layer){
  __shared__ float Wl[32*404];    // 32 rows x 400 (+4 pad) = 51.7KB
  __shared__ float hl[4*404];     // 4 bat x 400 (+4 pad)   = 6.5KB
  __shared__ float gb[32][5];     // gate dots [row][local bat]
  int tid = threadIdx.x;
  int bid = blockIdx.x;
  int dir     = bid / 200;
  int quarter = (bid / 50) % 4;
  int slice   = bid % 50;
  int jj0  = slice * 8;
  int bat0 = quarter * 4;
  int fbase = dir*200 + quarter*50;            // own gang's flag base
  const float* whhL = whh + (size_t)(layer*2 + dir)*1600*400;
  for (int i = tid; i < 3200; i += 128){        // 32 rows * 100 float4
    int r = i/100, k4 = i%100;
    int g = r>>3, jjr = r&7;
    float4 v = *(const float4*)(whhL + (size_t)(g*400 + jj0 + jjr)*400 + k4*4);
    *(float4*)&Wl[r*404 + k4*4] = v;
  }
  for (int i = tid; i < 4*404; i += 128) hl[i] = 0.f;
  // dot roles: ks 16-way (bits 2-5), rowg = bits 0-1 + bit 6 (8 groups)
  int ks   = (tid>>2)&15;
  int rowg = (tid&3) | ((tid>>6)<<2);
  const float* hb = hl;
  const float* wb = Wl + rowg*4*404;
  // epilogue roles (tid<32): one (bat,jj)
  int ebl = (tid>>3)&3;                         // local bat 0..3
  int ejj = tid & 7;
  int ebat = bat0 + ebl;
  const float* gbase = G + (size_t)ebat*96*3200 + dir*1600 + jj0 + ejj;
  float* xo = xout + (size_t)ebat*96*800 + dir*400 + jj0 + ejj;
  float c = 0.f;
  float g0=0.f, g1=0.f, g2=0.f, g3=0.f;
  if (tid < 32){
    const float* gp0 = gbase + (size_t)(dir ? 95 : 0)*3200;
    g0 = gp0[0]; g1 = gp0[400]; g2 = gp0[800]; g3 = gp0[1200];
  }
  // per-thread flag indices guarding own h-loads (slice = jj/8)
  const unsigned* fl0 = flags + (size_t)(fbase + (tid>>3))*16;        // hA
  const unsigned* fl1 = flags + (size_t)(fbase + 16 + (tid>>3))*16;   // hB
  const unsigned* fl2 = flags + (size_t)(fbase + 32 + (tid>>3))*16;   // hC
  const unsigned* flt = flags + (size_t)(fbase + 48 + ((tid&15)>>3))*16; // tail
  __syncthreads();
  for (int s = 0; s < 96; s++){
    int t = dir ? 95 - s : s;
    // ---- dot phase: k4 = q*16 + ks (q=0..5), tail k4 = 96+ks for ks<4 ----
    float acc[4][4] = {};
    #pragma unroll
    for (int q = 0; q < 6; ++q){
      int k4 = q*16 + ks;
      float4 h0 = *(const float4*)&hb[0*404 + k4*4];
      float4 h1 = *(const float4*)&hb[1*404 + k4*4];
      float4 h2 = *(const float4*)&hb[2*404 + k4*4];
      float4 h3 = *(const float4*)&hb[3*404 + k4*4];
      float4 w0 = *(const float4*)&wb[0*404 + k4*4];
      float4 w1 = *(const float4*)&wb[1*404 + k4*4];
      float4 w2 = *(const float4*)&wb[2*404 + k4*4];
      float4 w3 = *(const float4*)&wb[3*404 + k4*4];
      #pragma unroll
      for (int bi=0; bi<4; bi++){
        float4 hq = bi==0?h0: bi==1?h1: bi==2?h2: h3;
        #pragma unroll
        for (int ri=0; ri<4; ri++){
          float4 wq = ri==0?w0: ri==1?w1: ri==2?w2: w3;
          acc[bi][ri] = fmaf(hq.x,wq.x, fmaf(hq.y,wq.y,
                        fmaf(hq.z,wq.z, fmaf(hq.w,wq.w, acc[bi][ri]))));
        }
      }
    }
    if (ks < 4){                               // tail k4 = 96..99
      int k4 = 96 + ks;
      float4 h0 = *(const float4*)&hb[0*404 + k4*4];
      float4 h1 = *(const float4*)&hb[1*404 + k4*4];
      float4 h2 = *(const float4*)&hb[2*404 + k4*4];
      float4 h3 = *(const float4*)&hb[3*404 + k4*4];
      float4 w0 = *(const float4*)&wb[0*404 + k4*4];
      float4 w1 = *(const float4*)&wb[1*404 + k4*4];
      float4 w2 = *(const float4*)&wb[2*404 + k4*4];
      float4 w3 = *(const float4*)&wb[3*404 + k4*4];
      #pragma unroll
      for (int bi=0; bi<4; bi++){
        float4 hq = bi==0?h0: bi==1?h1: bi==2?h2: h3;
        #pragma unroll
        for (int ri=0; ri<4; ri++){
          float4 wq = ri==0?w0: ri==1?w1: ri==2?w2: w3;
          acc[bi][ri] = fmaf(hq.x,wq.x, fmaf(hq.y,wq.y,
                        fmaf(hq.z,wq.z, fmaf(hq.w,wq.w, acc[bi][ri]))));
        }
      }
    }
    // k-split reduce over ks (lane bits 2-5)
    #pragma unroll
    for (int bi=0; bi<4; bi++)
      #pragma unroll
      for (int ri=0; ri<4; ri++){
        float v = acc[bi][ri];
        v += __shfl_xor(v, 4);
        v += __shfl_xor(v, 8);
        v += __shfl_xor(v, 16);
        v += __shfl_xor(v, 32);
        acc[bi][ri] = v;
      }
    if (ks == 0){
      #pragma unroll
      for (int ri=0; ri<4; ri++)
        #pragma unroll
        for (int bi=0; bi<4; bi++)
          gb[rowg*4+ri][bi] = acc[bi][ri];
    }
    __syncthreads();                 // (A) gb ready; hl reads of this step done
    int par = s & 1;
    unsigned target = (unsigned)(layer*95 + s + 1);
    float hv = 0.f;
    if (tid < 32){                   // epilogue (wave0 lanes 0-31)
      float ai = gb[     ejj][ebl] + g0;
      float af = gb[ 8 + ejj][ebl] + g1;
      float ag = gb[16 + ejj][ebl] + g2;
      float ao = gb[24 + ejj][ebl] + g3;
      c = sigf(af)*c + sigf(ai)*tanhf(ag);
      hv = sigf(ao)*tanhf(c);
      if (s < 95)
        agent_st(&hbufG[((size_t)(par*2 + dir)*16 + ebat)*400 + jj0 + ejj], hv);
    }
    if (s < 95 && tid < 64){         // wave0: drain own publishes, raise flag
      asm volatile("s_waitcnt vmcnt(0)" ::: "memory");
      if (tid == 0)
        __hip_atomic_store(&flags[bid*16], target, __ATOMIC_RELAXED,
                           __HIP_MEMORY_SCOPE_AGENT);
    }
    if (tid < 32){
      xo[(size_t)t*800] = hv;        // after flag: not part of the drain
      if (s < 95){                   // prefetch next-step G gates
        int tn = dir ? 94 - s : s + 1;
        const float* gp = gbase + (size_t)tn*3200;
        g0 = gp[0]; g1 = gp[400]; g2 = gp[800]; g3 = gp[1200];
      }
    }
    if (s < 95){
      // fine-grained: wait only own slices' flags, load right after each
      const float* hsrc = hbufG + (size_t)(par*2 + dir)*6400 + bat0*400;
      float hA[4], hB[4], hC[4], hT;
      while (flag_ld(fl0) < target) __builtin_amdgcn_s_sleep(1);
      #pragma unroll
      for (int bat = 0; bat < 4; bat++) hA[bat] = agent_ld(hsrc + bat*400 + tid);
      while (flag_ld(fl1) < target) __builtin_amdgcn_s_sleep(1);
      #pragma unroll
      for (int bat = 0; bat < 4; bat++) hB[bat] = agent_ld(hsrc + bat*400 + 128 + tid);
      while (flag_ld(fl2) < target) __builtin_amdgcn_s_sleep(1);
      #pragma unroll
      for (int bat = 0; bat < 4; bat++) hC[bat] = agent_ld(hsrc + bat*400 + 256 + tid);
      hT = 0.f;
      if (tid < 64){
        while (flag_ld(flt) < target) __builtin_amdgcn_s_sleep(1);
        hT = agent_ld(hsrc + (tid>>4)*400 + 384 + (tid&15));
      }
      #pragma unroll
      for (int bat = 0; bat < 4; bat++){
        hl[bat*404 + tid]       = hA[bat];
        hl[bat*404 + 128 + tid] = hB[bat];
        hl[bat*404 + 256 + tid] = hC[bat];
      }
      if (tid < 64) hl[(tid>>4)*404 + 384 + (tid&15)] = hT;
    }
    __syncthreads();                 // (B) hl ready for next dot
  }
}

// ---------- log_softmax over last axis of s_arc, write transposed p ----------
__global__ __launch_bounds__(256) void softmax_p(const float* __restrict__ sarc,
                                                 float* __restrict__ p){
  int row  = blockIdx.x*4 + (threadIdx.x >> 6);  // 0..1535  (b,x)
  int lane = threadIdx.x & 63;
  int b = row/96, x = row%96;
  const float* s = sarc + (long)(b*96 + x)*96;
  float v1 = s[lane];
  float v2 = (lane+64 < 96) ? s[lane+64] : -INFINITY;
  float mx = wred_max(fmaxf(v1,v2));
  float sm = wred_sum(__expf(v1-mx) + __expf(v2-mx));
  float lse = mx + __logf(sm);
  float* pr = p + (long)b*9216;
  pr[lane*96 + x] = v1 - lse;
  if (lane+64 < 96) pr[(lane+64)*96 + x] = v2 - lse;
}

// ---------- best_score ----------
__global__ __launch_bounds__(128) void best_kern(const float* __restrict__ p,
                                                 const float* __restrict__ multinomial,
                                                 const int* __restrict__ labels,
                                                 const int* __restrict__ heads,
                                                 float* __restrict__ best){
  int b = blockIdx.x, tid = threadIdx.x;
  float acc = 0.f;
  for (int ti = tid; ti < 95; ti += 128) {
    int y = heads[b*95 + ti];
    int x = ti + 1;
    acc += p[(long)b*9216 + y*96 + x]
         + multinomial[(long)labels[b*96 + y]*64 + labels[b*96 + x]];
  }
  acc = wred_sum(acc);
  __shared__ float tmp[2];
  if ((tid & 63) == 0) tmp[tid >> 6] = acc;
  __syncthreads();
  if (tid == 0) best[b] = tmp[0] + tmp[1];
}

// ---------- Eisner inside, task-parallel (r7) ----------
__global__ __launch_bounds__(1024) void inside_kern(const float* __restrict__ p,
                                                    float* __restrict__ part){
  __shared__ float Cp[96][97];
  __shared__ float Ipp[96][97];
  __shared__ float Xp[96][97];
  __shared__ float Pl[96][97];
  int b = blockIdx.x;
  const float* pB = p + (long)b*9216;
  int tid = threadIdx.x;
  for (int idx = tid; idx < 96*97; idx += 1024) {
    int row = idx/97, col = idx%97;
    float d = (row == col) ? 0.f : -1e9f;
    Cp[row][col] = d;
    Xp[row][col] = d;
    Ipp[row][col] = -1e9f;
  }
  for (int idx = tid; idx < 9216; idx += 1024)
    Pl[idx/96][idx%96] = pB[idx];
  __syncthreads();
  int g = tid >> 3, l = tid & 7;   // 128 groups of 8 lanes
  for (int w = 1; w < 96; w++){
    int n = 96 - w;
    if (g < n){
      int i = g, j = i + w;
      const float* pa  = &Cp[i][i];
      const float* pb2 = &Cp[j][i+1];
      float vb[12]; float m = -1e30f;
      #pragma unroll
      for (int k = 0; k < 12; k++){
        vb[k] = -1e30f;
        if (k*8 < w){
          int r = l + k*8;
          if (r < w){ float v = pa[r] + pb2[r]; vb[k] = v; m = fmaxf(m, v); }
        }
      }
      m = fmaxf(m, __shfl_xor(m,1));
      m = fmaxf(m, __shfl_xor(m,2));
      m = fmaxf(m, __shfl_xor(m,4));
      float s = 0.f;
      #pragma unroll
      for (int k = 0; k < 12; k++){
        if (k*8 < w) s += __expf(vb[k] - m);
      }
      s += __shfl_xor(s,1); s += __shfl_xor(s,2); s += __shfl_xor(s,4);
      if (l == 0){
        float inc = m + __logf(s);
        Ipp[i][j] = inc + Pl[i][j];
        Ipp[j][i] = inc + Pl[j][i];
      }
    }
    __syncthreads();
    for (int task = g; task < 2*n; task += 128){
      int typ = task < n ? 1 : 0;        // 1 = cr, 0 = cl
      int i = typ ? task : task - n;
      int j = i + w;
      const float* pa  = typ ? &Ipp[i][i+1] : &Xp[i][i];
      const float* pb2 = typ ? &Xp[j][i+1]  : &Ipp[j][i];
      float vb[12]; float m = -1e30f;
      #pragma unroll
      for (int k = 0; k < 12; k++){
        vb[k] = -1e30f;
        if (k*8 < w){
          int r = l + k*8;
          if (r < w){ float v = pa[r] + pb2[r]; vb[k] = v; m = fmaxf(m, v); }
        }
      }
      m = fmaxf(m, __shfl_xor(m,1));
      m = fmaxf(m, __shfl_xor(m,2));
      m = fmaxf(m, __shfl_xor(m,4));
      float s = 0.f;
      #pragma unroll
      for (int k = 0; k < 12; k++){
        if (k*8 < w) s += __expf(vb[k] - m);
      }
      s += __shfl_xor(s,1); s += __shfl_xor(s,2); s += __shfl_xor(s,4);
      if (l == 0){
        float res = m + __logf(s);
        if (typ){ Cp[i][j] = res; Xp[j][i] = res; }
        else    { Cp[j][i] = res; Xp[i][j] = res; }
      }
    }
    __syncthreads();
  }
  if (tid == 0) part[b] = Cp[0][95];
}

// ---------- final mean ----------
__global__ __launch_bounds__(64) void final_kern(const float* __restrict__ part,
                                                 const float* __restrict__ best,
                                                 float* __restrict__ out){
  int lane = threadIdx.x;
  float v = (lane < 16) ? part[lane] - best[lane] : 0.f;
  v = wred_sum(v);
  if (lane == 0) out[0] = v * (1.f/16.f);
}

extern "C" void kernel_launch(void* const* d_in, const int* in_sizes, int n_in,
                              void* d_out, int out_size, void* d_ws, size_t ws_size,
                              hipStream_t stream) {
  const float* emb   = (const float*)d_in[0];
  const float* multi = (const float*)d_in[1];
  const float* wih0  = (const float*)d_in[2];
  const float* wih   = (const float*)d_in[3];
  const float* whh   = (const float*)d_in[4];
  const float* bias  = (const float*)d_in[5];
  const float* mhw   = (const float*)d_in[6];
  const float* mhb   = (const float*)d_in[7];
  const float* mdw   = (const float*)d_in[8];
  const float* mdb   = (const float*)d_in[9];
  const float* biaf  = (const float*)d_in[10];
  const int*   labels= (const int*)d_in[11];
  const int*   heads = (const int*)d_in[12];
  float* out = (float*)d_out;

  float* ws = (float*)d_ws;
  size_t off = 0;
  auto alloc = [&](size_t n){ float* q = ws + off; off += n; return q; };
  float* G    = alloc(1536L*3200);
  float* x0   = alloc(1536L*768);
  float* xA   = alloc(1536L*800);
  float* xB   = alloc(1536L*800);
  float* WTb  = alloc(500L*500);
  float* arcH = alloc(1536L*500);
  float* arcD = alloc(1536L*500);
  float* tmp  = alloc(1536L*500);
  float* sarc = alloc(16L*96*96);
  float* pbuf = alloc(16L*96*96);
  float* hbufG= alloc(2L*2*16*400);
  unsigned* flags = (unsigned*)alloc(NBLK_LSTM*16);
  float* part = alloc(16);
  float* best = alloc(16);
  (void)ws_size; (void)in_sizes; (void)n_in; (void)out_size;

  hipMemsetAsync(flags, 0, NBLK_LSTM*16*sizeof(unsigned), stream);

  embed_kern<<<(1536*768)/256, 256, 0, stream>>>(emb, labels, x0);
  trans_sq<<<(250000+255)/256, 256, 0, stream>>>(biaf, WTb);

  const float* xin = x0;
  float* xout = xA;
  for (int l = 0; l < 3; l++) {
    int Kd = (l==0) ? 768 : 800;
    const float* W = (l==0) ? wih0 : wih + (size_t)(l-1)*2*1600*800;
    gemm128<<<dim3(12,25), 256, 0, stream>>>(xin, W, G, bias + l*3200,
                                             1536, 3200, Kd, 0);
    lstm_grid<<<NBLK_LSTM, 128, 0, stream>>>(G, whh, xout, hbufG, flags, l);
    xin = xout;
    xout = (l==0) ? xB : xA;
  }
  // xin == xA (l0:x0->xA, l1:xA->xB, l2:xB->xA)
  dim3 gm(24, 8, 1);
  gemm_abt<<<gm, 256, 0, stream>>>(xin,  mhw, arcH, mhb, 1536, 500, 800, 0,0,0, 1);
  gemm_abt<<<gm, 256, 0, stream>>>(xin,  mdw, arcD, mdb, 1536, 500, 800, 0,0,0, 1);
  gemm_abt<<<gm, 256, 0, stream>>>(arcD, WTb, tmp, nullptr, 1536, 500, 500, 0,0,0, 0);
  dim3 gs(2, 2, 16);
  gemm_abt<<<gs, 256, 0, stream>>>(tmp, arcH, sarc, nullptr, 96, 96, 500,
                                   96L*500, 96L*500, 96L*96, 0);
  softmax_p<<<384, 256, 0, stream>>>(sarc, pbuf);
  best_kern<<<16, 128, 0, stream>>>(pbuf, multi, labels, heads, best);
  inside_kern<<<16, 1024, 0, stream>>>(pbuf, part);
  final_kern<<<1, 64, 0, stream>>>(part, best, out);
}

// Round 15
// 2163.786 us; speedup vs baseline: 1.1164x; 1.1164x over previous
//
#include <hip/hip_runtime.h>
#include <cmath>

#define DEV __device__ __forceinline__

// ---------- constants ----------
// B=16, T=96, K=64, D=768, H=400, L=3, M=500
// BT = 1536, 4H = 1600, both dirs = 3200, 2H = 800
// NOTE: the LSTM stack is chaotic (||Whh||~6): recurrence must be fp32-exact
// (fp16 W failed, r2). fp32 k-split reassociation is safe (r8/r12 passed).
// Sync history: r4 counter barrier ~14us/step; r5 threadfence = L2 walks;
// r6 fence-free agent atomics WIN; r10 optimistic sentinel loads REGRESSED;
// r14 fine-grained per-thread flag polling REGRESSED (~500 concurrent flag
// loads/block hammer the coherent point; r13's 50 pollers + block barrier
// is the measured optimum). LESSON: flag-then-load, loads issued exactly
// once, FEW pollers.
// Dot history: r7 4-way k-split bank-perfect; r8 8-way contiguous aliased;
// r11 W-in-registers spilled; r12 half-split WIN 545->407; r13 quarter-split
// WIN 407->388 (400 blk = dir x quarter x 50 slices, 32 rows x 4 bats).
// r15: lstm_grid = r13 VERBATIM; keep r14's MLP 64x64-tile GEMMs (+105us).

#define NBLK_LSTM 400

DEV float wred_max(float v){ for(int o=32;o;o>>=1) v=fmaxf(v,__shfl_xor(v,o)); return v; }
DEV float wred_sum(float v){ for(int o=32;o;o>>=1) v+=__shfl_xor(v,o); return v; }
DEV float sigf(float x){ return 1.f/(1.f+__expf(-x)); }

DEV float agent_ld(const float* p){
  return __hip_atomic_load(p, __ATOMIC_RELAXED, __HIP_MEMORY_SCOPE_AGENT);
}
DEV void agent_st(float* p, float v){
  __hip_atomic_store(p, v, __ATOMIC_RELAXED, __HIP_MEMORY_SCOPE_AGENT);
}

// ---------- embedding gather ----------
__global__ __launch_bounds__(256) void embed_kern(const float* __restrict__ tab,
                                                  const int* __restrict__ labels,
                                                  float* __restrict__ x0){
  long idx = (long)blockIdx.x*256 + threadIdx.x;   // BT*768
  if (idx >= 1536L*768) return;
  int m = (int)(idx/768), d = (int)(idx%768);
  x0[idx] = tab[(long)labels[m]*768 + d];
}

// ---------- transpose biaffine 500x500 ----------
__global__ __launch_bounds__(256) void trans_sq(const float* __restrict__ w,
                                                float* __restrict__ wt){
  int idx = blockIdx.x*256 + threadIdx.x;          // 250,000
  if (idx >= 250000) return;
  int j = idx/500, i = idx%500;
  wt[idx] = w[(long)i*500 + j];                    // wt[j][i] = w[i][j]
}

// ---------- 64x64 fp32 GEMM ----------
__global__ __launch_bounds__(256) void gemm_abt(const float* __restrict__ A,
                                                const float* __restrict__ Bm,
                                                float* __restrict__ C,
                                                const float* __restrict__ bias,
                                                int M, int N, int K,
                                                long sA, long sB, long sC, int leaky){
  A  += (long)blockIdx.z * sA;
  Bm += (long)blockIdx.z * sB;
  C  += (long)blockIdx.z * sC;
  __shared__ float As[16][68];
  __shared__ float Bs[16][68];
  int tid = threadIdx.x;
  int tx = tid & 15, ty = tid >> 4;
  int m0 = blockIdx.x * 64, n0 = blockIdx.y * 64;
  int lrow = tid >> 2, lc = (tid & 3) * 4;
  float acc[4][4] = {};
  for (int k0 = 0; k0 < K; k0 += 16) {
    #pragma unroll
    for (int u = 0; u < 4; u++) {
      int k = k0 + lc + u;
      int am = m0 + lrow;
      As[lc+u][lrow] = (am < M && k < K) ? A[(long)am*K + k] : 0.f;
      int bn = n0 + lrow;
      Bs[lc+u][lrow] = (bn < N && k < K) ? Bm[(long)bn*K + k] : 0.f;
    }
    __syncthreads();
    #pragma unroll
    for (int kk = 0; kk < 16; kk++) {
      float a[4], bb[4];
      #pragma unroll
      for (int u=0;u<4;u++){ a[u]=As[kk][ty*4+u]; bb[u]=Bs[kk][tx*4+u]; }
      #pragma unroll
      for (int i=0;i<4;i++)
        #pragma unroll
        for (int j=0;j<4;j++) acc[i][j] = fmaf(a[i], bb[j], acc[i][j]);
    }
    __syncthreads();
  }
  #pragma unroll
  for (int i=0;i<4;i++){
    int m = m0 + ty*4 + i;
    if (m >= M) continue;
    #pragma unroll
    for (int j=0;j<4;j++){
      int n = n0 + tx*4 + j;
      if (n >= N) continue;
      float v = acc[i][j];
      if (bias) v += bias[n];
      if (leaky) v = v > 0.f ? v : 0.1f*v;
      C[(long)m*N + n] = v;
    }
  }
}

// ---------- 128x128 fp32 GEMM: C[m,n] = sum_k A[m,k]*B[n,k] (+bias,leaky) ----
__global__ __launch_bounds__(256) void gemm128(const float* __restrict__ A,
                                               const float* __restrict__ Bm,
                                               float* __restrict__ C,
                                               const float* __restrict__ bias,
                                               int M, int N, int K, int leaky){
  __shared__ float As[16][132];
  __shared__ float Bs[16][132];
  int tid = threadIdx.x;
  int tx = tid & 15, ty = tid >> 4;
  int m0 = blockIdx.x*128, n0 = blockIdx.y*128;
  int lr = tid >> 1, lq = (tid & 1)*8;
  const float* Arow = A + (size_t)(m0+lr)*K + lq;
  const float* Brow = Bm + (size_t)(n0+lr)*K + lq;
  bool bok = (n0 + lr) < N;
  float acc[8][8] = {};
  for (int k0 = 0; k0 < K; k0 += 16){
    if (k0 + 16 <= K){
      float4 a0 = *(const float4*)(Arow + k0);
      float4 a1 = *(const float4*)(Arow + k0 + 4);
      float4 b0 = {0,0,0,0}, b1 = {0,0,0,0};
      if (bok){ b0 = *(const float4*)(Brow + k0); b1 = *(const float4*)(Brow + k0 + 4); }
      As[lq+0][lr]=a0.x; As[lq+1][lr]=a0.y; As[lq+2][lr]=a0.z; As[lq+3][lr]=a0.w;
      As[lq+4][lr]=a1.x; As[lq+5][lr]=a1.y; As[lq+6][lr]=a1.z; As[lq+7][lr]=a1.w;
      Bs[lq+0][lr]=b0.x; Bs[lq+1][lr]=b0.y; Bs[lq+2][lr]=b0.z; Bs[lq+3][lr]=b0.w;
      Bs[lq+4][lr]=b1.x; Bs[lq+5][lr]=b1.y; Bs[lq+6][lr]=b1.z; Bs[lq+7][lr]=b1.w;
    } else {
      #pragma unroll
      for (int u = 0; u < 8; u++){
        int k = k0 + lq + u;
        As[lq+u][lr] = (k < K) ? Arow[k0+u] : 0.f;
        Bs[lq+u][lr] = (bok && k < K) ? Brow[k0+u] : 0.f;
      }
    }
    __syncthreads();
    #pragma unroll
    for (int kk = 0; kk < 16; kk++){
      float4 a0 = *(const float4*)&As[kk][ty*8];
      float4 a1 = *(const float4*)&As[kk][ty*8+4];
      float4 b0 = *(const float4*)&Bs[kk][tx*8];
      float4 b1 = *(const float4*)&Bs[kk][tx*8+4];
      float av[8] = {a0.x,a0.y,a0.z,a0.w,a1.x,a1.y,a1.z,a1.w};
      float bv[8] = {b0.x,b0.y,b0.z,b0.w,b1.x,b1.y,b1.z,b1.w};
      #pragma unroll
      for (int i=0;i<8;i++)
        #pragma unroll
        for (int j=0;j<8;j++) acc[i][j] = fmaf(av[i], bv[j], acc[i][j]);
    }
    __syncthreads();
  }
  bool full = (n0 + 128 <= N);
  #pragma unroll
  for (int i = 0; i < 8; i++){
    int m = m0 + ty*8 + i;
    float* Crow = C + (size_t)m*N;
    if (full){
      float4 v0, v1;
      float* p0 = &v0.x; float* p1 = &v1.x;
      #pragma unroll
      for (int j = 0; j < 4; j++){
        int n = n0 + tx*8 + j;
        float v = acc[i][j];
        if (bias) v += bias[n];
        if (leaky) v = v > 0.f ? v : 0.1f*v;
        p0[j] = v;
      }
      #pragma unroll
      for (int j = 4; j < 8; j++){
        int n = n0 + tx*8 + j;
        float v = acc[i][j];
        if (bias) v += bias[n];
        if (leaky) v = v > 0.f ? v : 0.1f*v;
        p1[j-4] = v;
      }
      *(float4*)(Crow + n0 + tx*8)     = v0;
      *(float4*)(Crow + n0 + tx*8 + 4) = v1;
    } else {
      #pragma unroll
      for (int j = 0; j < 8; j++){
        int n = n0 + tx*8 + j;
        if (n < N){
          float v = acc[i][j];
          if (bias) v += bias[n];
          if (leaky) v = v > 0.f ? v : 0.1f*v;
          Crow[n] = v;
        }
      }
    }
  }
}

// ---------- weight-stationary grid-synced LSTM (one layer, 96 steps) --------
// r13 VERBATIM (the measured optimum). 400 blocks = dir(2) x quarter(4) x
// slice(50). Block: 32 W-rows (8 jj x 4 gates) x 4 bats. Dot: ks=(tid>>2)&15
// (16-way, interleaved k4 = q*16+ks); rowg=(tid&3)|((tid>>6)<<2). Bank audit:
// h reads 2-way free; W reads 4-way priced. shfl_xor 4/8/16/32 reduce.
// Epilogue tid<32, one (bat,jj). Sync: publish h (agent_st) -> syncthreads
// (vmcnt drain) -> tid0 flag -> tid<50 polls own gang's 50 flags -> reload
// 4 bats (13 loads/thread). FEW pollers (r14 lesson).
__global__ __launch_bounds__(128) void lstm_grid(const float* __restrict__ G,
                                                 const float* __restrict__ whh,
                                                 float* __restrict__ xout,
                                                 float* __restrict__ hbufG,
                                                 unsigned* __restrict__ flags,
                                                 int layer){
  __shared__ float Wl[32*404];    // 32 rows x 400 (+4 pad) = 51.7KB
  __shared__ float hl[4*404];     // 4 bat x 400 (+4 pad)   = 6.5KB
  __shared__ float gb[32][5];     // gate dots [row][local bat]
  int tid = threadIdx.x;
  int bid = blockIdx.x;
  int dir     = bid / 200;
  int quarter = (bid / 50) % 4;
  int slice   = bid % 50;
  int jj0  = slice * 8;
  int bat0 = quarter * 4;
  int fbase = dir*200 + quarter*50;            // own gang's flag base
  const float* whhL = whh + (size_t)(layer*2 + dir)*1600*400;
  for (int i = tid; i < 3200; i += 128){        // 32 rows * 100 float4
    int r = i/100, k4 = i%100;
    int g = r>>3, jjr = r&7;
    float4 v = *(const float4*)(whhL + (size_t)(g*400 + jj0 + jjr)*400 + k4*4);
    *(float4*)&Wl[r*404 + k4*4] = v;
  }
  for (int i = tid; i < 4*404; i += 128) hl[i] = 0.f;
  // dot roles: ks 16-way (bits 2-5), rowg = bits 0-1 + bit 6 (8 groups)
  int ks   = (tid>>2)&15;
  int rowg = (tid&3) | ((tid>>6)<<2);
  const float* hb = hl;
  const float* wb = Wl + rowg*4*404;
  // epilogue roles (tid<32): one (bat,jj)
  int ebl = (tid>>3)&3;                         // local bat 0..3
  int ejj = tid & 7;
  int ebat = bat0 + ebl;
  const float* gbase = G + (size_t)ebat*96*3200 + dir*1600 + jj0 + ejj;
  float* xo = xout + (size_t)ebat*96*800 + dir*400 + jj0 + ejj;
  float c = 0.f;
  float g0=0.f, g1=0.f, g2=0.f, g3=0.f;
  if (tid < 32){
    const float* gp0 = gbase + (size_t)(dir ? 95 : 0)*3200;
    g0 = gp0[0]; g1 = gp0[400]; g2 = gp0[800]; g3 = gp0[1200];
  }
  __syncthreads();
  for (int s = 0; s < 96; s++){
    int t = dir ? 95 - s : s;
    // ---- dot phase: k4 = q*16 + ks (q=0..5), tail k4 = 96+ks for ks<4 ----
    float acc[4][4] = {};
    #pragma unroll
    for (int q = 0; q < 6; ++q){
      int k4 = q*16 + ks;
      float4 h0 = *(const float4*)&hb[0*404 + k4*4];
      float4 h1 = *(const float4*)&hb[1*404 + k4*4];
      float4 h2 = *(const float4*)&hb[2*404 + k4*4];
      float4 h3 = *(const float4*)&hb[3*404 + k4*4];
      float4 w0 = *(const float4*)&wb[0*404 + k4*4];
      float4 w1 = *(const float4*)&wb[1*404 + k4*4];
      float4 w2 = *(const float4*)&wb[2*404 + k4*4];
      float4 w3 = *(const float4*)&wb[3*404 + k4*4];
      #pragma unroll
      for (int bi=0; bi<4; bi++){
        float4 hq = bi==0?h0: bi==1?h1: bi==2?h2: h3;
        #pragma unroll
        for (int ri=0; ri<4; ri++){
          float4 wq = ri==0?w0: ri==1?w1: ri==2?w2: w3;
          acc[bi][ri] = fmaf(hq.x,wq.x, fmaf(hq.y,wq.y,
                        fmaf(hq.z,wq.z, fmaf(hq.w,wq.w, acc[bi][ri]))));
        }
      }
    }
    if (ks < 4){                               // tail k4 = 96..99
      int k4 = 96 + ks;
      float4 h0 = *(const float4*)&hb[0*404 + k4*4];
      float4 h1 = *(const float4*)&hb[1*404 + k4*4];
      float4 h2 = *(const float4*)&hb[2*404 + k4*4];
      float4 h3 = *(const float4*)&hb[3*404 + k4*4];
      float4 w0 = *(const float4*)&wb[0*404 + k4*4];
      float4 w1 = *(const float4*)&wb[1*404 + k4*4];
      float4 w2 = *(const float4*)&wb[2*404 + k4*4];
      float4 w3 = *(const float4*)&wb[3*404 + k4*4];
      #pragma unroll
      for (int bi=0; bi<4; bi++){
        float4 hq = bi==0?h0: bi==1?h1: bi==2?h2: h3;
        #pragma unroll
        for (int ri=0; ri<4; ri++){
          float4 wq = ri==0?w0: ri==1?w1: ri==2?w2: w3;
          acc[bi][ri] = fmaf(hq.x,wq.x, fmaf(hq.y,wq.y,
                        fmaf(hq.z,wq.z, fmaf(hq.w,wq.w, acc[bi][ri]))));
        }
      }
    }
    // k-split reduce over ks (lane bits 2-5)
    #pragma unroll
    for (int bi=0; bi<4; bi++)
      #pragma unroll
      for (int ri=0; ri<4; ri++){
        float v = acc[bi][ri];
        v += __shfl_xor(v, 4);
        v += __shfl_xor(v, 8);
        v += __shfl_xor(v, 16);
        v += __shfl_xor(v, 32);
        acc[bi][ri] = v;
      }
    if (ks == 0){
      #pragma unroll
      for (int ri=0; ri<4; ri++)
        #pragma unroll
        for (int bi=0; bi<4; bi++)
          gb[rowg*4+ri][bi] = acc[bi][ri];
    }
    __syncthreads();                 // gb ready; hl reads of this step done
    // ---- epilogue (tid<32): gates -> c, h; publish ----
    int par = s & 1;
    if (tid < 32){
      float ai = gb[     ejj][ebl] + g0;
      float af = gb[ 8 + ejj][ebl] + g1;
      float ag = gb[16 + ejj][ebl] + g2;
      float ao = gb[24 + ejj][ebl] + g3;
      c = sigf(af)*c + sigf(ai)*tanhf(ag);
      float hv = sigf(ao)*tanhf(c);
      agent_st(&hbufG[((size_t)(par*2 + dir)*16 + ebat)*400 + jj0 + ejj], hv);
      xo[(size_t)t*800] = hv;
    }
    if (s < 95){
      unsigned target = (unsigned)(layer*95 + s + 1);
      __syncthreads();   // all waves vmcnt(0): h stores ack'd at coherent pt
      if (tid == 0)
        __hip_atomic_store(&flags[bid*16], target, __ATOMIC_RELAXED,
                           __HIP_MEMORY_SCOPE_AGENT);
      if (tid < 32){     // prefetch next-step G gates under the spin
        int tn = dir ? 94 - s : s + 1;
        const float* gp = gbase + (size_t)tn*3200;
        g0 = gp[0]; g1 = gp[400]; g2 = gp[800]; g3 = gp[1200];
      }
      if (tid < 50){     // wait on own (dir,quarter) gang only
        while (__hip_atomic_load(&flags[(fbase + tid)*16], __ATOMIC_RELAXED,
                                 __HIP_MEMORY_SCOPE_AGENT) < target){
          __builtin_amdgcn_s_sleep(1);
        }
      }
      __syncthreads();
      // reload own quarter's 4 bats: 1600 floats, 13 loads/thread
      const float* hsrc = hbufG + (size_t)(par*2 + dir)*6400 + bat0*400;
      float hA[4], hB[4], hC[4], hT;
      #pragma unroll
      for (int bat = 0; bat < 4; bat++){
        hA[bat] = agent_ld(hsrc + bat*400 + tid);
        hB[bat] = agent_ld(hsrc + bat*400 + 128 + tid);
        hC[bat] = agent_ld(hsrc + bat*400 + 256 + tid);
      }
      hT = (tid < 64) ? agent_ld(hsrc + (tid>>4)*400 + 384 + (tid&15)) : 0.f;
      #pragma unroll
      for (int bat = 0; bat < 4; bat++){
        hl[bat*404 + tid]       = hA[bat];
        hl[bat*404 + 128 + tid] = hB[bat];
        hl[bat*404 + 256 + tid] = hC[bat];
      }
      if (tid < 64) hl[(tid>>4)*404 + 384 + (tid&15)] = hT;
      __syncthreads();
    }
  }
}

// ---------- log_softmax over last axis of s_arc, write transposed p ----------
__global__ __launch_bounds__(256) void softmax_p(const float* __restrict__ sarc,
                                                 float* __restrict__ p){
  int row  = blockIdx.x*4 + (threadIdx.x >> 6);  // 0..1535  (b,x)
  int lane = threadIdx.x & 63;
  int b = row/96, x = row%96;
  const float* s = sarc + (long)(b*96 + x)*96;
  float v1 = s[lane];
  float v2 = (lane+64 < 96) ? s[lane+64] : -INFINITY;
  float mx = wred_max(fmaxf(v1,v2));
  float sm = wred_sum(__expf(v1-mx) + __expf(v2-mx));
  float lse = mx + __logf(sm);
  float* pr = p + (long)b*9216;
  pr[lane*96 + x] = v1 - lse;
  if (lane+64 < 96) pr[(lane+64)*96 + x] = v2 - lse;
}

// ---------- best_score ----------
__global__ __launch_bounds__(128) void best_kern(const float* __restrict__ p,
                                                 const float* __restrict__ multinomial,
                                                 const int* __restrict__ labels,
                                                 const int* __restrict__ heads,
                                                 float* __restrict__ best){
  int b = blockIdx.x, tid = threadIdx.x;
  float acc = 0.f;
  for (int ti = tid; ti < 95; ti += 128) {
    int y = heads[b*95 + ti];
    int x = ti + 1;
    acc += p[(long)b*9216 + y*96 + x]
         + multinomial[(long)labels[b*96 + y]*64 + labels[b*96 + x]];
  }
  acc = wred_sum(acc);
  __shared__ float tmp[2];
  if ((tid & 63) == 0) tmp[tid >> 6] = acc;
  __syncthreads();
  if (tid == 0) best[b] = tmp[0] + tmp[1];
}

// ---------- Eisner inside, task-parallel (r7) ----------
__global__ __launch_bounds__(1024) void inside_kern(const float* __restrict__ p,
                                                    float* __restrict__ part){
  __shared__ float Cp[96][97];
  __shared__ float Ipp[96][97];
  __shared__ float Xp[96][97];
  __shared__ float Pl[96][97];
  int b = blockIdx.x;
  const float* pB = p + (long)b*9216;
  int tid = threadIdx.x;
  for (int idx = tid; idx < 96*97; idx += 1024) {
    int row = idx/97, col = idx%97;
    float d = (row == col) ? 0.f : -1e9f;
    Cp[row][col] = d;
    Xp[row][col] = d;
    Ipp[row][col] = -1e9f;
  }
  for (int idx = tid; idx < 9216; idx += 1024)
    Pl[idx/96][idx%96] = pB[idx];
  __syncthreads();
  int g = tid >> 3, l = tid & 7;   // 128 groups of 8 lanes
  for (int w = 1; w < 96; w++){
    int n = 96 - w;
    if (g < n){
      int i = g, j = i + w;
      const float* pa  = &Cp[i][i];
      const float* pb2 = &Cp[j][i+1];
      float vb[12]; float m = -1e30f;
      #pragma unroll
      for (int k = 0; k < 12; k++){
        vb[k] = -1e30f;
        if (k*8 < w){
          int r = l + k*8;
          if (r < w){ float v = pa[r] + pb2[r]; vb[k] = v; m = fmaxf(m, v); }
        }
      }
      m = fmaxf(m, __shfl_xor(m,1));
      m = fmaxf(m, __shfl_xor(m,2));
      m = fmaxf(m, __shfl_xor(m,4));
      float s = 0.f;
      #pragma unroll
      for (int k = 0; k < 12; k++){
        if (k*8 < w) s += __expf(vb[k] - m);
      }
      s += __shfl_xor(s,1); s += __shfl_xor(s,2); s += __shfl_xor(s,4);
      if (l == 0){
        float inc = m + __logf(s);
        Ipp[i][j] = inc + Pl[i][j];
        Ipp[j][i] = inc + Pl[j][i];
      }
    }
    __syncthreads();
    for (int task = g; task < 2*n; task += 128){
      int typ = task < n ? 1 : 0;        // 1 = cr, 0 = cl
      int i = typ ? task : task - n;
      int j = i + w;
      const float* pa  = typ ? &Ipp[i][i+1] : &Xp[i][i];
      const float* pb2 = typ ? &Xp[j][i+1]  : &Ipp[j][i];
      float vb[12]; float m = -1e30f;
      #pragma unroll
      for (int k = 0; k < 12; k++){
        vb[k] = -1e30f;
        if (k*8 < w){
          int r = l + k*8;
          if (r < w){ float v = pa[r] + pb2[r]; vb[k] = v; m = fmaxf(m, v); }
        }
      }
      m = fmaxf(m, __shfl_xor(m,1));
      m = fmaxf(m, __shfl_xor(m,2));
      m = fmaxf(m, __shfl_xor(m,4));
      float s = 0.f;
      #pragma unroll
      for (int k = 0; k < 12; k++){
        if (k*8 < w) s += __expf(vb[k] - m);
      }
      s += __shfl_xor(s,1); s += __shfl_xor(s,2); s += __shfl_xor(s,4);
      if (l == 0){
        float res = m + __logf(s);
        if (typ){ Cp[i][j] = res; Xp[j][i] = res; }
        else    { Cp[j][i] = res; Xp[i][j] = res; }
      }
    }
    __syncthreads();
  }
  if (tid == 0) part[b] = Cp[0][95];
}

// ---------- final mean ----------
__global__ __launch_bounds__(64) void final_kern(const float* __restrict__ part,
                                                 const float* __restrict__ best,
                                                 float* __restrict__ out){
  int lane = threadIdx.x;
  float v = (lane < 16) ? part[lane] - best[lane] : 0.f;
  v = wred_sum(v);
  if (lane == 0) out[0] = v * (1.f/16.f);
}

extern "C" void kernel_launch(void* const* d_in, const int* in_sizes, int n_in,
                              void* d_out, int out_size, void* d_ws, size_t ws_size,
                              hipStream_t stream) {
  const float* emb   = (const float*)d_in[0];
  const float* multi = (const float*)d_in[1];
  const float* wih0  = (const float*)d_in[2];
  const float* wih   = (const float*)d_in[3];
  const float* whh   = (const float*)d_in[4];
  const float* bias  = (const float*)d_in[5];
  const float* mhw   = (const float*)d_in[6];
  const float* mhb   = (const float*)d_in[7];
  const float* mdw   = (const float*)d_in[8];
  const float* mdb   = (const float*)d_in[9];
  const float* biaf  = (const float*)d_in[10];
  const int*   labels= (const int*)d_in[11];
  const int*   heads = (const int*)d_in[12];
  float* out = (float*)d_out;

  float* ws = (float*)d_ws;
  size_t off = 0;
  auto alloc = [&](size_t n){ float* q = ws + off; off += n; return q; };
  float* G    = alloc(1536L*3200);
  float* x0   = alloc(1536L*768);
  float* xA   = alloc(1536L*800);
  float* xB   = alloc(1536L*800);
  float* WTb  = alloc(500L*500);
  float* arcH = alloc(1536L*500);
  float* arcD = alloc(1536L*500);
  float* tmp  = alloc(1536L*500);
  float* sarc = alloc(16L*96*96);
  float* pbuf = alloc(16L*96*96);
  float* hbufG= alloc(2L*2*16*400);
  unsigned* flags = (unsigned*)alloc(NBLK_LSTM*16);
  float* part = alloc(16);
  float* best = alloc(16);
  (void)ws_size; (void)in_sizes; (void)n_in; (void)out_size;

  hipMemsetAsync(flags, 0, NBLK_LSTM*16*sizeof(unsigned), stream);

  embed_kern<<<(1536*768)/256, 256, 0, stream>>>(emb, labels, x0);
  trans_sq<<<(250000+255)/256, 256, 0, stream>>>(biaf, WTb);

  const float* xin = x0;
  float* xout = xA;
  for (int l = 0; l < 3; l++) {
    int Kd = (l==0) ? 768 : 800;
    const float* W = (l==0) ? wih0 : wih + (size_t)(l-1)*2*1600*800;
    gemm128<<<dim3(12,25), 256, 0, stream>>>(xin, W, G, bias + l*3200,
                                             1536, 3200, Kd, 0);
    lstm_grid<<<NBLK_LSTM, 128, 0, stream>>>(G, whh, xout, hbufG, flags, l);
    xin = xout;
    xout = (l==0) ? xB : xA;
  }
  // xin == xA (l0:x0->xA, l1:xA->xB, l2:xB->xA)
  dim3 gm(24, 8, 1);
  gemm_abt<<<gm, 256, 0, stream>>>(xin,  mhw, arcH, mhb, 1536, 500, 800, 0,0,0, 1);
  gemm_abt<<<gm, 256, 0, stream>>>(xin,  mdw, arcD, mdb, 1536, 500, 800, 0,0,0, 1);
  gemm_abt<<<gm, 256, 0, stream>>>(arcD, WTb, tmp, nullptr, 1536, 500, 500, 0,0,0, 0);
  dim3 gs(2, 2, 16);
  gemm_abt<<<gs, 256, 0, stream>>>(tmp, arcH, sarc, nullptr, 96, 96, 500,
                                   96L*500, 96L*500, 96L*96, 0);
  softmax_p<<<384, 256, 0, stream>>>(sarc, pbuf);
  best_kern<<<16, 128, 0, stream>>>(pbuf, multi, labels, heads, best);
  inside_kern<<<16, 1024, 0, stream>>>(pbuf, part);
  final_kern<<<1, 64, 0, stream>>>(part, best, out);
}

// Round 16
// 2037.636 us; speedup vs baseline: 1.1855x; 1.0619x over previous
//
#include <hip/hip_runtime.h>
#include <cmath>

#define DEV __device__ __forceinline__

// ---------- constants ----------
// B=16, T=96, K=64, D=768, H=400, L=3, M=500
// BT = 1536, 4H = 1600, both dirs = 3200, 2H = 800
// NOTE: the LSTM stack is chaotic (||Whh||~6): recurrence must be fp32-exact
// (fp16 W failed, r2). fp32 k-split reassociation is safe (r8/r12 passed).
// Sync history: r4 counter barrier ~14us/step; r5 threadfence = L2 walks;
// r6 fence-free agent atomics WIN; r10 optimistic sentinel loads REGRESSED;
// r14 fine-grained per-thread polling REGRESSED (too many pollers hammer
// the coherent point). LESSON: flag-then-load, loads once, FEW pollers.
// Dot history: r7 bank-perfect 4-way; r8 aliased 8-way REGRESSED; r11
// W-in-regs spilled; r12 half-split WIN; r13 quarter-split WIN (388us).
// r15 = r13 lstm + 64x64 MLP tiles = 2164us best.
// r16: inside_kern barrier fusion — phase B needs only own-span ir/il from
// phase A (all 8 lanes of a group share a wave: lane0 LDS write then group
// reads is same-wave program order, no barrier) -> 1 barrier/width (95 vs
// 190), no double-shot at w<32. + arcH/arcD fused into one 384-blk launch.

#define NBLK_LSTM 400

DEV float wred_max(float v){ for(int o=32;o;o>>=1) v=fmaxf(v,__shfl_xor(v,o)); return v; }
DEV float wred_sum(float v){ for(int o=32;o;o>>=1) v+=__shfl_xor(v,o); return v; }
DEV float sigf(float x){ return 1.f/(1.f+__expf(-x)); }

DEV float agent_ld(const float* p){
  return __hip_atomic_load(p, __ATOMIC_RELAXED, __HIP_MEMORY_SCOPE_AGENT);
}
DEV void agent_st(float* p, float v){
  __hip_atomic_store(p, v, __ATOMIC_RELAXED, __HIP_MEMORY_SCOPE_AGENT);
}

// ---------- embedding gather ----------
__global__ __launch_bounds__(256) void embed_kern(const float* __restrict__ tab,
                                                  const int* __restrict__ labels,
                                                  float* __restrict__ x0){
  long idx = (long)blockIdx.x*256 + threadIdx.x;   // BT*768
  if (idx >= 1536L*768) return;
  int m = (int)(idx/768), d = (int)(idx%768);
  x0[idx] = tab[(long)labels[m]*768 + d];
}

// ---------- transpose biaffine 500x500 ----------
__global__ __launch_bounds__(256) void trans_sq(const float* __restrict__ w,
                                                float* __restrict__ wt){
  int idx = blockIdx.x*256 + threadIdx.x;          // 250,000
  if (idx >= 250000) return;
  int j = idx/500, i = idx%500;
  wt[idx] = w[(long)i*500 + j];                    // wt[j][i] = w[i][j]
}

// ---------- 64x64 fp32 GEMM ----------
__global__ __launch_bounds__(256) void gemm_abt(const float* __restrict__ A,
                                                const float* __restrict__ Bm,
                                                float* __restrict__ C,
                                                const float* __restrict__ bias,
                                                int M, int N, int K,
                                                long sA, long sB, long sC, int leaky){
  A  += (long)blockIdx.z * sA;
  Bm += (long)blockIdx.z * sB;
  C  += (long)blockIdx.z * sC;
  __shared__ float As[16][68];
  __shared__ float Bs[16][68];
  int tid = threadIdx.x;
  int tx = tid & 15, ty = tid >> 4;
  int m0 = blockIdx.x * 64, n0 = blockIdx.y * 64;
  int lrow = tid >> 2, lc = (tid & 3) * 4;
  float acc[4][4] = {};
  for (int k0 = 0; k0 < K; k0 += 16) {
    #pragma unroll
    for (int u = 0; u < 4; u++) {
      int k = k0 + lc + u;
      int am = m0 + lrow;
      As[lc+u][lrow] = (am < M && k < K) ? A[(long)am*K + k] : 0.f;
      int bn = n0 + lrow;
      Bs[lc+u][lrow] = (bn < N && k < K) ? Bm[(long)bn*K + k] : 0.f;
    }
    __syncthreads();
    #pragma unroll
    for (int kk = 0; kk < 16; kk++) {
      float a[4], bb[4];
      #pragma unroll
      for (int u=0;u<4;u++){ a[u]=As[kk][ty*4+u]; bb[u]=Bs[kk][tx*4+u]; }
      #pragma unroll
      for (int i=0;i<4;i++)
        #pragma unroll
        for (int j=0;j<4;j++) acc[i][j] = fmaf(a[i], bb[j], acc[i][j]);
    }
    __syncthreads();
  }
  #pragma unroll
  for (int i=0;i<4;i++){
    int m = m0 + ty*4 + i;
    if (m >= M) continue;
    #pragma unroll
    for (int j=0;j<4;j++){
      int n = n0 + tx*4 + j;
      if (n >= N) continue;
      float v = acc[i][j];
      if (bias) v += bias[n];
      if (leaky) v = v > 0.f ? v : 0.1f*v;
      C[(long)m*N + n] = v;
    }
  }
}

// ---------- fused arcH+arcD MLP GEMM: z=0 -> arcH, z=1 -> arcD -----------
// C[m,n] = leaky(sum_k A[m,k]*W[n,k] + b[n]), M=1536, N=500, K=800.
__global__ __launch_bounds__(256) void mlp2_kern(const float* __restrict__ A,
                                                 const float* __restrict__ Wh,
                                                 const float* __restrict__ bh,
                                                 const float* __restrict__ Wd,
                                                 const float* __restrict__ bd,
                                                 float* __restrict__ Ch,
                                                 float* __restrict__ Cd){
  const float* Bm  = blockIdx.z ? Wd : Wh;
  const float* bias= blockIdx.z ? bd : bh;
  float* C         = blockIdx.z ? Cd : Ch;
  const int M = 1536, N = 500, K = 800;
  __shared__ float As[16][68];
  __shared__ float Bs[16][68];
  int tid = threadIdx.x;
  int tx = tid & 15, ty = tid >> 4;
  int m0 = blockIdx.x * 64, n0 = blockIdx.y * 64;
  int lrow = tid >> 2, lc = (tid & 3) * 4;
  float acc[4][4] = {};
  for (int k0 = 0; k0 < K; k0 += 16) {
    #pragma unroll
    for (int u = 0; u < 4; u++) {
      int k = k0 + lc + u;
      As[lc+u][lrow] = A[(long)(m0+lrow)*K + k];
      int bn = n0 + lrow;
      Bs[lc+u][lrow] = (bn < N) ? Bm[(long)bn*K + k] : 0.f;
    }
    __syncthreads();
    #pragma unroll
    for (int kk = 0; kk < 16; kk++) {
      float a[4], bb[4];
      #pragma unroll
      for (int u=0;u<4;u++){ a[u]=As[kk][ty*4+u]; bb[u]=Bs[kk][tx*4+u]; }
      #pragma unroll
      for (int i=0;i<4;i++)
        #pragma unroll
        for (int j=0;j<4;j++) acc[i][j] = fmaf(a[i], bb[j], acc[i][j]);
    }
    __syncthreads();
  }
  #pragma unroll
  for (int i=0;i<4;i++){
    int m = m0 + ty*4 + i;
    #pragma unroll
    for (int j=0;j<4;j++){
      int n = n0 + tx*4 + j;
      if (n >= N) continue;
      float v = acc[i][j] + bias[n];
      v = v > 0.f ? v : 0.1f*v;
      C[(long)m*N + n] = v;
    }
  }
}

// ---------- 128x128 fp32 GEMM: C[m,n] = sum_k A[m,k]*B[n,k] (+bias,leaky) ----
__global__ __launch_bounds__(256) void gemm128(const float* __restrict__ A,
                                               const float* __restrict__ Bm,
                                               float* __restrict__ C,
                                               const float* __restrict__ bias,
                                               int M, int N, int K, int leaky){
  __shared__ float As[16][132];
  __shared__ float Bs[16][132];
  int tid = threadIdx.x;
  int tx = tid & 15, ty = tid >> 4;
  int m0 = blockIdx.x*128, n0 = blockIdx.y*128;
  int lr = tid >> 1, lq = (tid & 1)*8;
  const float* Arow = A + (size_t)(m0+lr)*K + lq;
  const float* Brow = Bm + (size_t)(n0+lr)*K + lq;
  bool bok = (n0 + lr) < N;
  float acc[8][8] = {};
  for (int k0 = 0; k0 < K; k0 += 16){
    if (k0 + 16 <= K){
      float4 a0 = *(const float4*)(Arow + k0);
      float4 a1 = *(const float4*)(Arow + k0 + 4);
      float4 b0 = {0,0,0,0}, b1 = {0,0,0,0};
      if (bok){ b0 = *(const float4*)(Brow + k0); b1 = *(const float4*)(Brow + k0 + 4); }
      As[lq+0][lr]=a0.x; As[lq+1][lr]=a0.y; As[lq+2][lr]=a0.z; As[lq+3][lr]=a0.w;
      As[lq+4][lr]=a1.x; As[lq+5][lr]=a1.y; As[lq+6][lr]=a1.z; As[lq+7][lr]=a1.w;
      Bs[lq+0][lr]=b0.x; Bs[lq+1][lr]=b0.y; Bs[lq+2][lr]=b0.z; Bs[lq+3][lr]=b0.w;
      Bs[lq+4][lr]=b1.x; Bs[lq+5][lr]=b1.y; Bs[lq+6][lr]=b1.z; Bs[lq+7][lr]=b1.w;
    } else {
      #pragma unroll
      for (int u = 0; u < 8; u++){
        int k = k0 + lq + u;
        As[lq+u][lr] = (k < K) ? Arow[k0+u] : 0.f;
        Bs[lq+u][lr] = (bok && k < K) ? Brow[k0+u] : 0.f;
      }
    }
    __syncthreads();
    #pragma unroll
    for (int kk = 0; kk < 16; kk++){
      float4 a0 = *(const float4*)&As[kk][ty*8];
      float4 a1 = *(const float4*)&As[kk][ty*8+4];
      float4 b0 = *(const float4*)&Bs[kk][tx*8];
      float4 b1 = *(const float4*)&Bs[kk][tx*8+4];
      float av[8] = {a0.x,a0.y,a0.z,a0.w,a1.x,a1.y,a1.z,a1.w};
      float bv[8] = {b0.x,b0.y,b0.z,b0.w,b1.x,b1.y,b1.z,b1.w};
      #pragma unroll
      for (int i=0;i<8;i++)
        #pragma unroll
        for (int j=0;j<8;j++) acc[i][j] = fmaf(av[i], bv[j], acc[i][j]);
    }
    __syncthreads();
  }
  bool full = (n0 + 128 <= N);
  #pragma unroll
  for (int i = 0; i < 8; i++){
    int m = m0 + ty*8 + i;
    float* Crow = C + (size_t)m*N;
    if (full){
      float4 v0, v1;
      float* p0 = &v0.x; float* p1 = &v1.x;
      #pragma unroll
      for (int j = 0; j < 4; j++){
        int n = n0 + tx*8 + j;
        float v = acc[i][j];
        if (bias) v += bias[n];
        if (leaky) v = v > 0.f ? v : 0.1f*v;
        p0[j] = v;
      }
      #pragma unroll
      for (int j = 4; j < 8; j++){
        int n = n0 + tx*8 + j;
        float v = acc[i][j];
        if (bias) v += bias[n];
        if (leaky) v = v > 0.f ? v : 0.1f*v;
        p1[j-4] = v;
      }
      *(float4*)(Crow + n0 + tx*8)     = v0;
      *(float4*)(Crow + n0 + tx*8 + 4) = v1;
    } else {
      #pragma unroll
      for (int j = 0; j < 8; j++){
        int n = n0 + tx*8 + j;
        if (n < N){
          float v = acc[i][j];
          if (bias) v += bias[n];
          if (leaky) v = v > 0.f ? v : 0.1f*v;
          Crow[n] = v;
        }
      }
    }
  }
}

// ---------- weight-stationary grid-synced LSTM (one layer, 96 steps) --------
// r13 VERBATIM (measured optimum). 400 blocks = dir(2) x quarter(4) x
// slice(50). Block: 32 W-rows x 4 bats. Dot: ks=(tid>>2)&15 interleaved;
// rowg=(tid&3)|((tid>>6)<<2). Sync: publish h -> syncthreads -> tid0 flag ->
// tid<50 polls own gang's flags -> reload 4 bats. FEW pollers (r14 lesson).
__global__ __launch_bounds__(128) void lstm_grid(const float* __restrict__ G,
                                                 const float* __restrict__ whh,
                                                 float* __restrict__ xout,
                                                 float* __restrict__ hbufG,
                                                 unsigned* __restrict__ flags,
                                                 int layer){
  __shared__ float Wl[32*404];    // 32 rows x 400 (+4 pad) = 51.7KB
  __shared__ float hl[4*404];     // 4 bat x 400 (+4 pad)   = 6.5KB
  __shared__ float gb[32][5];     // gate dots [row][local bat]
  int tid = threadIdx.x;
  int bid = blockIdx.x;
  int dir     = bid / 200;
  int quarter = (bid / 50) % 4;
  int slice   = bid % 50;
  int jj0  = slice * 8;
  int bat0 = quarter * 4;
  int fbase = dir*200 + quarter*50;            // own gang's flag base
  const float* whhL = whh + (size_t)(layer*2 + dir)*1600*400;
  for (int i = tid; i < 3200; i += 128){        // 32 rows * 100 float4
    int r = i/100, k4 = i%100;
    int g = r>>3, jjr = r&7;
    float4 v = *(const float4*)(whhL + (size_t)(g*400 + jj0 + jjr)*400 + k4*4);
    *(float4*)&Wl[r*404 + k4*4] = v;
  }
  for (int i = tid; i < 4*404; i += 128) hl[i] = 0.f;
  int ks   = (tid>>2)&15;
  int rowg = (tid&3) | ((tid>>6)<<2);
  const float* hb = hl;
  const float* wb = Wl + rowg*4*404;
  int ebl = (tid>>3)&3;                         // local bat 0..3
  int ejj = tid & 7;
  int ebat = bat0 + ebl;
  const float* gbase = G + (size_t)ebat*96*3200 + dir*1600 + jj0 + ejj;
  float* xo = xout + (size_t)ebat*96*800 + dir*400 + jj0 + ejj;
  float c = 0.f;
  float g0=0.f, g1=0.f, g2=0.f, g3=0.f;
  if (tid < 32){
    const float* gp0 = gbase + (size_t)(dir ? 95 : 0)*3200;
    g0 = gp0[0]; g1 = gp0[400]; g2 = gp0[800]; g3 = gp0[1200];
  }
  __syncthreads();
  for (int s = 0; s < 96; s++){
    int t = dir ? 95 - s : s;
    float acc[4][4] = {};
    #pragma unroll
    for (int q = 0; q < 6; ++q){
      int k4 = q*16 + ks;
      float4 h0 = *(const float4*)&hb[0*404 + k4*4];
      float4 h1 = *(const float4*)&hb[1*404 + k4*4];
      float4 h2 = *(const float4*)&hb[2*404 + k4*4];
      float4 h3 = *(const float4*)&hb[3*404 + k4*4];
      float4 w0 = *(const float4*)&wb[0*404 + k4*4];
      float4 w1 = *(const float4*)&wb[1*404 + k4*4];
      float4 w2 = *(const float4*)&wb[2*404 + k4*4];
      float4 w3 = *(const float4*)&wb[3*404 + k4*4];
      #pragma unroll
      for (int bi=0; bi<4; bi++){
        float4 hq = bi==0?h0: bi==1?h1: bi==2?h2: h3;
        #pragma unroll
        for (int ri=0; ri<4; ri++){
          float4 wq = ri==0?w0: ri==1?w1: ri==2?w2: w3;
          acc[bi][ri] = fmaf(hq.x,wq.x, fmaf(hq.y,wq.y,
                        fmaf(hq.z,wq.z, fmaf(hq.w,wq.w, acc[bi][ri]))));
        }
      }
    }
    if (ks < 4){                               // tail k4 = 96..99
      int k4 = 96 + ks;
      float4 h0 = *(const float4*)&hb[0*404 + k4*4];
      float4 h1 = *(const float4*)&hb[1*404 + k4*4];
      float4 h2 = *(const float4*)&hb[2*404 + k4*4];
      float4 h3 = *(const float4*)&hb[3*404 + k4*4];
      float4 w0 = *(const float4*)&wb[0*404 + k4*4];
      float4 w1 = *(const float4*)&wb[1*404 + k4*4];
      float4 w2 = *(const float4*)&wb[2*404 + k4*4];
      float4 w3 = *(const float4*)&wb[3*404 + k4*4];
      #pragma unroll
      for (int bi=0; bi<4; bi++){
        float4 hq = bi==0?h0: bi==1?h1: bi==2?h2: h3;
        #pragma unroll
        for (int ri=0; ri<4; ri++){
          float4 wq = ri==0?w0: ri==1?w1: ri==2?w2: w3;
          acc[bi][ri] = fmaf(hq.x,wq.x, fmaf(hq.y,wq.y,
                        fmaf(hq.z,wq.z, fmaf(hq.w,wq.w, acc[bi][ri]))));
        }
      }
    }
    #pragma unroll
    for (int bi=0; bi<4; bi++)
      #pragma unroll
      for (int ri=0; ri<4; ri++){
        float v = acc[bi][ri];
        v += __shfl_xor(v, 4);
        v += __shfl_xor(v, 8);
        v += __shfl_xor(v, 16);
        v += __shfl_xor(v, 32);
        acc[bi][ri] = v;
      }
    if (ks == 0){
      #pragma unroll
      for (int ri=0; ri<4; ri++)
        #pragma unroll
        for (int bi=0; bi<4; bi++)
          gb[rowg*4+ri][bi] = acc[bi][ri];
    }
    __syncthreads();
    int par = s & 1;
    if (tid < 32){
      float ai = gb[     ejj][ebl] + g0;
      float af = gb[ 8 + ejj][ebl] + g1;
      float ag = gb[16 + ejj][ebl] + g2;
      float ao = gb[24 + ejj][ebl] + g3;
      c = sigf(af)*c + sigf(ai)*tanhf(ag);
      float hv = sigf(ao)*tanhf(c);
      agent_st(&hbufG[((size_t)(par*2 + dir)*16 + ebat)*400 + jj0 + ejj], hv);
      xo[(size_t)t*800] = hv;
    }
    if (s < 95){
      unsigned target = (unsigned)(layer*95 + s + 1);
      __syncthreads();
      if (tid == 0)
        __hip_atomic_store(&flags[bid*16], target, __ATOMIC_RELAXED,
                           __HIP_MEMORY_SCOPE_AGENT);
      if (tid < 32){
        int tn = dir ? 94 - s : s + 1;
        const float* gp = gbase + (size_t)tn*3200;
        g0 = gp[0]; g1 = gp[400]; g2 = gp[800]; g3 = gp[1200];
      }
      if (tid < 50){
        while (__hip_atomic_load(&flags[(fbase + tid)*16], __ATOMIC_RELAXED,
                                 __HIP_MEMORY_SCOPE_AGENT) < target){
          __builtin_amdgcn_s_sleep(1);
        }
      }
      __syncthreads();
      const float* hsrc = hbufG + (size_t)(par*2 + dir)*6400 + bat0*400;
      float hA[4], hB[4], hC[4], hT;
      #pragma unroll
      for (int bat = 0; bat < 4; bat++){
        hA[bat] = agent_ld(hsrc + bat*400 + tid);
        hB[bat] = agent_ld(hsrc + bat*400 + 128 + tid);
        hC[bat] = agent_ld(hsrc + bat*400 + 256 + tid);
      }
      hT = (tid < 64) ? agent_ld(hsrc + (tid>>4)*400 + 384 + (tid&15)) : 0.f;
      #pragma unroll
      for (int bat = 0; bat < 4; bat++){
        hl[bat*404 + tid]       = hA[bat];
        hl[bat*404 + 128 + tid] = hB[bat];
        hl[bat*404 + 256 + tid] = hC[bat];
      }
      if (tid < 64) hl[(tid>>4)*404 + 384 + (tid&15)] = hT;
      __syncthreads();
    }
  }
}

// ---------- log_softmax over last axis of s_arc, write transposed p ----------
__global__ __launch_bounds__(256) void softmax_p(const float* __restrict__ sarc,
                                                 float* __restrict__ p){
  int row  = blockIdx.x*4 + (threadIdx.x >> 6);  // 0..1535  (b,x)
  int lane = threadIdx.x & 63;
  int b = row/96, x = row%96;
  const float* s = sarc + (long)(b*96 + x)*96;
  float v1 = s[lane];
  float v2 = (lane+64 < 96) ? s[lane+64] : -INFINITY;
  float mx = wred_max(fmaxf(v1,v2));
  float sm = wred_sum(__expf(v1-mx) + __expf(v2-mx));
  float lse = mx + __logf(sm);
  float* pr = p + (long)b*9216;
  pr[lane*96 + x] = v1 - lse;
  if (lane+64 < 96) pr[(lane+64)*96 + x] = v2 - lse;
}

// ---------- best_score ----------
__global__ __launch_bounds__(128) void best_kern(const float* __restrict__ p,
                                                 const float* __restrict__ multinomial,
                                                 const int* __restrict__ labels,
                                                 const int* __restrict__ heads,
                                                 float* __restrict__ best){
  int b = blockIdx.x, tid = threadIdx.x;
  float acc = 0.f;
  for (int ti = tid; ti < 95; ti += 128) {
    int y = heads[b*95 + ti];
    int x = ti + 1;
    acc += p[(long)b*9216 + y*96 + x]
         + multinomial[(long)labels[b*96 + y]*64 + labels[b*96 + x]];
  }
  acc = wred_sum(acc);
  __shared__ float tmp[2];
  if ((tid & 63) == 0) tmp[tid >> 6] = acc;
  __syncthreads();
  if (tid == 0) best[b] = tmp[0] + tmp[1];
}

// ---------- Eisner inside, task-parallel + fused phases (r16) ----------
// Storage (96x97, diag shared): Cp upper C_r / lower C_l^T; Ipp upper I_r /
// lower I_l^T; Xp upper C_l / lower C_r^T; Pl = p.
// r16: ONE barrier per width. Group (8 lanes, same wave) for span (i,j):
// computes inc -> ir,il; lane0 writes Ipp[i][j], Ipp[j][i]; same-wave
// program order makes them visible to the group's own cr/cl reads (lane w-1
// reads Ipp[i][j]=ir, lane 0 reads Ipp[j][i]=il) — no barrier. All other
// intra-width reads touch strictly smaller widths. Math identical to r7.
__global__ __launch_bounds__(1024) void inside_kern(const float* __restrict__ p,
                                                    float* __restrict__ part){
  __shared__ float Cp[96][97];
  __shared__ float Ipp[96][97];
  __shared__ float Xp[96][97];
  __shared__ float Pl[96][97];
  int b = blockIdx.x;
  const float* pB = p + (long)b*9216;
  int tid = threadIdx.x;
  for (int idx = tid; idx < 96*97; idx += 1024) {
    int row = idx/97, col = idx%97;
    float d = (row == col) ? 0.f : -1e9f;
    Cp[row][col] = d;
    Xp[row][col] = d;
    Ipp[row][col] = -1e9f;
  }
  for (int idx = tid; idx < 9216; idx += 1024)
    Pl[idx/96][idx%96] = pB[idx];
  __syncthreads();
  int g = tid >> 3, l = tid & 7;   // 128 groups of 8 lanes (same wave)
  for (int w = 1; w < 96; w++){
    int n = 96 - w;
    if (g < n){
      int i = g, j = i + w;
      // ---- inc = lse_r Cp[i][i+r] + Cp[j][i+1+r], r=0..w-1 ----
      {
        const float* pa  = &Cp[i][i];
        const float* pb2 = &Cp[j][i+1];
        float vb[12]; float m = -1e30f;
        #pragma unroll
        for (int k = 0; k < 12; k++){
          vb[k] = -1e30f;
          if (k*8 < w){
            int r = l + k*8;
            if (r < w){ float v = pa[r] + pb2[r]; vb[k] = v; m = fmaxf(m, v); }
          }
        }
        m = fmaxf(m, __shfl_xor(m,1));
        m = fmaxf(m, __shfl_xor(m,2));
        m = fmaxf(m, __shfl_xor(m,4));
        float s = 0.f;
        #pragma unroll
        for (int k = 0; k < 12; k++){
          if (k*8 < w) s += __expf(vb[k] - m);
        }
        s += __shfl_xor(s,1); s += __shfl_xor(s,2); s += __shfl_xor(s,4);
        float inc = m + __logf(s);
        if (l == 0){
          Ipp[i][j] = inc + Pl[i][j];
          Ipp[j][i] = inc + Pl[j][i];
        }
      }
      // same-wave LDS write->read: visible without barrier
      // ---- cr = lse_r Ipp[i][i+1+r] + Xp[j][i+1+r]  (r=w-1 reads ir) ----
      // ---- cl = lse_r Xp[i][i+r]    + Ipp[j][i+r]   (r=0   reads il) ----
      {
        const float* pa1 = &Ipp[i][i+1];
        const float* pb1 = &Xp[j][i+1];
        const float* pa2 = &Xp[i][i];
        const float* pb2 = &Ipp[j][i];
        float v1b[12], v2b[12]; float m1 = -1e30f, m2 = -1e30f;
        #pragma unroll
        for (int k = 0; k < 12; k++){
          v1b[k] = -1e30f; v2b[k] = -1e30f;
          if (k*8 < w){
            int r = l + k*8;
            if (r < w){
              float v1 = pa1[r] + pb1[r]; v1b[k] = v1; m1 = fmaxf(m1, v1);
              float v2 = pa2[r] + pb2[r]; v2b[k] = v2; m2 = fmaxf(m2, v2);
            }
          }
        }
        m1 = fmaxf(m1, __shfl_xor(m1,1));
        m1 = fmaxf(m1, __shfl_xor(m1,2));
        m1 = fmaxf(m1, __shfl_xor(m1,4));
        m2 = fmaxf(m2, __shfl_xor(m2,1));
        m2 = fmaxf(m2, __shfl_xor(m2,2));
        m2 = fmaxf(m2, __shfl_xor(m2,4));
        float s1 = 0.f, s2 = 0.f;
        #pragma unroll
        for (int k = 0; k < 12; k++){
          if (k*8 < w){ s1 += __expf(v1b[k] - m1); s2 += __expf(v2b[k] - m2); }
        }
        s1 += __shfl_xor(s1,1); s1 += __shfl_xor(s1,2); s1 += __shfl_xor(s1,4);
        s2 += __shfl_xor(s2,1); s2 += __shfl_xor(s2,2); s2 += __shfl_xor(s2,4);
        if (l == 0){
          float cr = m1 + __logf(s1);
          float cl = m2 + __logf(s2);
          Cp[i][j] = cr; Xp[j][i] = cr;
          Cp[j][i] = cl; Xp[i][j] = cl;
        }
      }
    }
    __syncthreads();
  }
  if (tid == 0) part[b] = Cp[0][95];
}

// ---------- final mean ----------
__global__ __launch_bounds__(64) void final_kern(const float* __restrict__ part,
                                                 const float* __restrict__ best,
                                                 float* __restrict__ out){
  int lane = threadIdx.x;
  float v = (lane < 16) ? part[lane] - best[lane] : 0.f;
  v = wred_sum(v);
  if (lane == 0) out[0] = v * (1.f/16.f);
}

extern "C" void kernel_launch(void* const* d_in, const int* in_sizes, int n_in,
                              void* d_out, int out_size, void* d_ws, size_t ws_size,
                              hipStream_t stream) {
  const float* emb   = (const float*)d_in[0];
  const float* multi = (const float*)d_in[1];
  const float* wih0  = (const float*)d_in[2];
  const float* wih   = (const float*)d_in[3];
  const float* whh   = (const float*)d_in[4];
  const float* bias  = (const float*)d_in[5];
  const float* mhw   = (const float*)d_in[6];
  const float* mhb   = (const float*)d_in[7];
  const float* mdw   = (const float*)d_in[8];
  const float* mdb   = (const float*)d_in[9];
  const float* biaf  = (const float*)d_in[10];
  const int*   labels= (const int*)d_in[11];
  const int*   heads = (const int*)d_in[12];
  float* out = (float*)d_out;

  float* ws = (float*)d_ws;
  size_t off = 0;
  auto alloc = [&](size_t n){ float* q = ws + off; off += n; return q; };
  float* G    = alloc(1536L*3200);
  float* x0   = alloc(1536L*768);
  float* xA   = alloc(1536L*800);
  float* xB   = alloc(1536L*800);
  float* WTb  = alloc(500L*500);
  float* arcH = alloc(1536L*500);
  float* arcD = alloc(1536L*500);
  float* tmp  = alloc(1536L*500);
  float* sarc = alloc(16L*96*96);
  float* pbuf = alloc(16L*96*96);
  float* hbufG= alloc(2L*2*16*400);
  unsigned* flags = (unsigned*)alloc(NBLK_LSTM*16);
  float* part = alloc(16);
  float* best = alloc(16);
  (void)ws_size; (void)in_sizes; (void)n_in; (void)out_size;

  hipMemsetAsync(flags, 0, NBLK_LSTM*16*sizeof(unsigned), stream);

  embed_kern<<<(1536*768)/256, 256, 0, stream>>>(emb, labels, x0);
  trans_sq<<<(250000+255)/256, 256, 0, stream>>>(biaf, WTb);

  const float* xin = x0;
  float* xout = xA;
  for (int l = 0; l < 3; l++) {
    int Kd = (l==0) ? 768 : 800;
    const float* W = (l==0) ? wih0 : wih + (size_t)(l-1)*2*1600*800;
    gemm128<<<dim3(12,25), 256, 0, stream>>>(xin, W, G, bias + l*3200,
                                             1536, 3200, Kd, 0);
    lstm_grid<<<NBLK_LSTM, 128, 0, stream>>>(G, whh, xout, hbufG, flags, l);
    xin = xout;
    xout = (l==0) ? xB : xA;
  }
  // xin == xA (l0:x0->xA, l1:xA->xB, l2:xB->xA)
  mlp2_kern<<<dim3(24,8,2), 256, 0, stream>>>(xin, mhw, mhb, mdw, mdb, arcH, arcD);
  dim3 gm(24, 8, 1);
  gemm_abt<<<gm, 256, 0, stream>>>(arcD, WTb, tmp, nullptr, 1536, 500, 500, 0,0,0, 0);
  dim3 gs(2, 2, 16);
  gemm_abt<<<gs, 256, 0, stream>>>(tmp, arcH, sarc, nullptr, 96, 96, 500,
                                   96L*500, 96L*500, 96L*96, 0);
  softmax_p<<<384, 256, 0, stream>>>(sarc, pbuf);
  best_kern<<<16, 128, 0, stream>>>(pbuf, multi, labels, heads, best);
  inside_kern<<<16, 1024, 0, stream>>>(pbuf, part);
  final_kern<<<1, 64, 0, stream>>>(part, best, out);
}

// Round 17
// 1970.489 us; speedup vs baseline: 1.2259x; 1.0341x over previous
//
#include <hip/hip_runtime.h>
#include <cmath>

#define DEV __device__ __forceinline__

// ---------- constants ----------
// B=16, T=96, K=64, D=768, H=400, L=3, M=500
// BT = 1536, 4H = 1600, both dirs = 3200, 2H = 800
// NOTE: the LSTM stack is chaotic (||Whh||~6): recurrence must be fp32-exact
// (fp16 W failed, r2). fp32 k-split reassociation is safe (r8/r12 passed).
// Sync: r6 fence-free agent atomics WIN; r10/r14 REGRESSED (lessons:
// flag-then-load, loads once, FEW pollers). Dot: r13 quarter-split = 388us
// optimum; r8/r11 regressions documented. r15 recombine = 2164; r16 inside
// 1-barrier fusion + mlp2 fusion = 2038.
// r17: layer-0 G-GEMM has only 64 DISTINCT input rows (embed_table) ->
// Gtab = emb@Wih0^T + b (64x3200, tiny gemm_abt, bit-identical k-order)
// then float4 gather G[bt] = Gtab[labels[bt]]. Replaces the ~115us
// layer-0 gemm128 AND embed_kern with ~15us total.

#define NBLK_LSTM 400

DEV float wred_max(float v){ for(int o=32;o;o>>=1) v=fmaxf(v,__shfl_xor(v,o)); return v; }
DEV float wred_sum(float v){ for(int o=32;o;o>>=1) v+=__shfl_xor(v,o); return v; }
DEV float sigf(float x){ return 1.f/(1.f+__expf(-x)); }

DEV float agent_ld(const float* p){
  return __hip_atomic_load(p, __ATOMIC_RELAXED, __HIP_MEMORY_SCOPE_AGENT);
}
DEV void agent_st(float* p, float v){
  __hip_atomic_store(p, v, __ATOMIC_RELAXED, __HIP_MEMORY_SCOPE_AGENT);
}

// ---------- gather G rows from Gtab (layer 0) ----------
__global__ __launch_bounds__(256) void g_gather(const float* __restrict__ Gtab,
                                                const int* __restrict__ labels,
                                                float* __restrict__ G){
  long idx = (long)blockIdx.x*256 + threadIdx.x;   // 1536*800 float4s
  if (idx >= 1536L*800) return;
  int bt = (int)(idx / 800), d4 = (int)(idx - (long)bt*800);
  const float4* src = (const float4*)(Gtab + (size_t)labels[bt]*3200) + d4;
  ((float4*)(G + (size_t)bt*3200))[d4] = *src;
}

// ---------- transpose biaffine 500x500 ----------
__global__ __launch_bounds__(256) void trans_sq(const float* __restrict__ w,
                                                float* __restrict__ wt){
  int idx = blockIdx.x*256 + threadIdx.x;          // 250,000
  if (idx >= 250000) return;
  int j = idx/500, i = idx%500;
  wt[idx] = w[(long)i*500 + j];                    // wt[j][i] = w[i][j]
}

// ---------- 64x64 fp32 GEMM ----------
__global__ __launch_bounds__(256) void gemm_abt(const float* __restrict__ A,
                                                const float* __restrict__ Bm,
                                                float* __restrict__ C,
                                                const float* __restrict__ bias,
                                                int M, int N, int K,
                                                long sA, long sB, long sC, int leaky){
  A  += (long)blockIdx.z * sA;
  Bm += (long)blockIdx.z * sB;
  C  += (long)blockIdx.z * sC;
  __shared__ float As[16][68];
  __shared__ float Bs[16][68];
  int tid = threadIdx.x;
  int tx = tid & 15, ty = tid >> 4;
  int m0 = blockIdx.x * 64, n0 = blockIdx.y * 64;
  int lrow = tid >> 2, lc = (tid & 3) * 4;
  float acc[4][4] = {};
  for (int k0 = 0; k0 < K; k0 += 16) {
    #pragma unroll
    for (int u = 0; u < 4; u++) {
      int k = k0 + lc + u;
      int am = m0 + lrow;
      As[lc+u][lrow] = (am < M && k < K) ? A[(long)am*K + k] : 0.f;
      int bn = n0 + lrow;
      Bs[lc+u][lrow] = (bn < N && k < K) ? Bm[(long)bn*K + k] : 0.f;
    }
    __syncthreads();
    #pragma unroll
    for (int kk = 0; kk < 16; kk++) {
      float a[4], bb[4];
      #pragma unroll
      for (int u=0;u<4;u++){ a[u]=As[kk][ty*4+u]; bb[u]=Bs[kk][tx*4+u]; }
      #pragma unroll
      for (int i=0;i<4;i++)
        #pragma unroll
        for (int j=0;j<4;j++) acc[i][j] = fmaf(a[i], bb[j], acc[i][j]);
    }
    __syncthreads();
  }
  #pragma unroll
  for (int i=0;i<4;i++){
    int m = m0 + ty*4 + i;
    if (m >= M) continue;
    #pragma unroll
    for (int j=0;j<4;j++){
      int n = n0 + tx*4 + j;
      if (n >= N) continue;
      float v = acc[i][j];
      if (bias) v += bias[n];
      if (leaky) v = v > 0.f ? v : 0.1f*v;
      C[(long)m*N + n] = v;
    }
  }
}

// ---------- fused arcH+arcD MLP GEMM: z=0 -> arcH, z=1 -> arcD -----------
__global__ __launch_bounds__(256) void mlp2_kern(const float* __restrict__ A,
                                                 const float* __restrict__ Wh,
                                                 const float* __restrict__ bh,
                                                 const float* __restrict__ Wd,
                                                 const float* __restrict__ bd,
                                                 float* __restrict__ Ch,
                                                 float* __restrict__ Cd){
  const float* Bm  = blockIdx.z ? Wd : Wh;
  const float* bias= blockIdx.z ? bd : bh;
  float* C         = blockIdx.z ? Cd : Ch;
  const int M = 1536, N = 500, K = 800;
  __shared__ float As[16][68];
  __shared__ float Bs[16][68];
  int tid = threadIdx.x;
  int tx = tid & 15, ty = tid >> 4;
  int m0 = blockIdx.x * 64, n0 = blockIdx.y * 64;
  int lrow = tid >> 2, lc = (tid & 3) * 4;
  float acc[4][4] = {};
  for (int k0 = 0; k0 < K; k0 += 16) {
    #pragma unroll
    for (int u = 0; u < 4; u++) {
      int k = k0 + lc + u;
      As[lc+u][lrow] = A[(long)(m0+lrow)*K + k];
      int bn = n0 + lrow;
      Bs[lc+u][lrow] = (bn < N) ? Bm[(long)bn*K + k] : 0.f;
    }
    __syncthreads();
    #pragma unroll
    for (int kk = 0; kk < 16; kk++) {
      float a[4], bb[4];
      #pragma unroll
      for (int u=0;u<4;u++){ a[u]=As[kk][ty*4+u]; bb[u]=Bs[kk][tx*4+u]; }
      #pragma unroll
      for (int i=0;i<4;i++)
        #pragma unroll
        for (int j=0;j<4;j++) acc[i][j] = fmaf(a[i], bb[j], acc[i][j]);
    }
    __syncthreads();
  }
  #pragma unroll
  for (int i=0;i<4;i++){
    int m = m0 + ty*4 + i;
    #pragma unroll
    for (int j=0;j<4;j++){
      int n = n0 + tx*4 + j;
      if (n >= N) continue;
      float v = acc[i][j] + bias[n];
      v = v > 0.f ? v : 0.1f*v;
      C[(long)m*N + n] = v;
    }
  }
}

// ---------- 128x128 fp32 GEMM: C[m,n] = sum_k A[m,k]*B[n,k] (+bias,leaky) ----
__global__ __launch_bounds__(256) void gemm128(const float* __restrict__ A,
                                               const float* __restrict__ Bm,
                                               float* __restrict__ C,
                                               const float* __restrict__ bias,
                                               int M, int N, int K, int leaky){
  __shared__ float As[16][132];
  __shared__ float Bs[16][132];
  int tid = threadIdx.x;
  int tx = tid & 15, ty = tid >> 4;
  int m0 = blockIdx.x*128, n0 = blockIdx.y*128;
  int lr = tid >> 1, lq = (tid & 1)*8;
  const float* Arow = A + (size_t)(m0+lr)*K + lq;
  const float* Brow = Bm + (size_t)(n0+lr)*K + lq;
  bool bok = (n0 + lr) < N;
  float acc[8][8] = {};
  for (int k0 = 0; k0 < K; k0 += 16){
    if (k0 + 16 <= K){
      float4 a0 = *(const float4*)(Arow + k0);
      float4 a1 = *(const float4*)(Arow + k0 + 4);
      float4 b0 = {0,0,0,0}, b1 = {0,0,0,0};
      if (bok){ b0 = *(const float4*)(Brow + k0); b1 = *(const float4*)(Brow + k0 + 4); }
      As[lq+0][lr]=a0.x; As[lq+1][lr]=a0.y; As[lq+2][lr]=a0.z; As[lq+3][lr]=a0.w;
      As[lq+4][lr]=a1.x; As[lq+5][lr]=a1.y; As[lq+6][lr]=a1.z; As[lq+7][lr]=a1.w;
      Bs[lq+0][lr]=b0.x; Bs[lq+1][lr]=b0.y; Bs[lq+2][lr]=b0.z; Bs[lq+3][lr]=b0.w;
      Bs[lq+4][lr]=b1.x; Bs[lq+5][lr]=b1.y; Bs[lq+6][lr]=b1.z; Bs[lq+7][lr]=b1.w;
    } else {
      #pragma unroll
      for (int u = 0; u < 8; u++){
        int k = k0 + lq + u;
        As[lq+u][lr] = (k < K) ? Arow[k0+u] : 0.f;
        Bs[lq+u][lr] = (bok && k < K) ? Brow[k0+u] : 0.f;
      }
    }
    __syncthreads();
    #pragma unroll
    for (int kk = 0; kk < 16; kk++){
      float4 a0 = *(const float4*)&As[kk][ty*8];
      float4 a1 = *(const float4*)&As[kk][ty*8+4];
      float4 b0 = *(const float4*)&Bs[kk][tx*8];
      float4 b1 = *(const float4*)&Bs[kk][tx*8+4];
      float av[8] = {a0.x,a0.y,a0.z,a0.w,a1.x,a1.y,a1.z,a1.w};
      float bv[8] = {b0.x,b0.y,b0.z,b0.w,b1.x,b1.y,b1.z,b1.w};
      #pragma unroll
      for (int i=0;i<8;i++)
        #pragma unroll
        for (int j=0;j<8;j++) acc[i][j] = fmaf(av[i], bv[j], acc[i][j]);
    }
    __syncthreads();
  }
  bool full = (n0 + 128 <= N);
  #pragma unroll
  for (int i = 0; i < 8; i++){
    int m = m0 + ty*8 + i;
    float* Crow = C + (size_t)m*N;
    if (full){
      float4 v0, v1;
      float* p0 = &v0.x; float* p1 = &v1.x;
      #pragma unroll
      for (int j = 0; j < 4; j++){
        int n = n0 + tx*8 + j;
        float v = acc[i][j];
        if (bias) v += bias[n];
        if (leaky) v = v > 0.f ? v : 0.1f*v;
        p0[j] = v;
      }
      #pragma unroll
      for (int j = 4; j < 8; j++){
        int n = n0 + tx*8 + j;
        float v = acc[i][j];
        if (bias) v += bias[n];
        if (leaky) v = v > 0.f ? v : 0.1f*v;
        p1[j-4] = v;
      }
      *(float4*)(Crow + n0 + tx*8)     = v0;
      *(float4*)(Crow + n0 + tx*8 + 4) = v1;
    } else {
      #pragma unroll
      for (int j = 0; j < 8; j++){
        int n = n0 + tx*8 + j;
        if (n < N){
          float v = acc[i][j];
          if (bias) v += bias[n];
          if (leaky) v = v > 0.f ? v : 0.1f*v;
          Crow[n] = v;
        }
      }
    }
  }
}

// ---------- weight-stationary grid-synced LSTM (one layer, 96 steps) --------
// r13 VERBATIM (measured optimum). 400 blocks = dir(2) x quarter(4) x
// slice(50). Block: 32 W-rows x 4 bats. Dot: ks=(tid>>2)&15 interleaved;
// rowg=(tid&3)|((tid>>6)<<2). Sync: publish h -> syncthreads -> tid0 flag ->
// tid<50 polls own gang's flags -> reload 4 bats. FEW pollers (r14 lesson).
__global__ __launch_bounds__(128) void lstm_grid(const float* __restrict__ G,
                                                 const float* __restrict__ whh,
                                                 float* __restrict__ xout,
                                                 float* __restrict__ hbufG,
                                                 unsigned* __restrict__ flags,
                                                 int layer){
  __shared__ float Wl[32*404];    // 32 rows x 400 (+4 pad) = 51.7KB
  __shared__ float hl[4*404];     // 4 bat x 400 (+4 pad)   = 6.5KB
  __shared__ float gb[32][5];     // gate dots [row][local bat]
  int tid = threadIdx.x;
  int bid = blockIdx.x;
  int dir     = bid / 200;
  int quarter = (bid / 50) % 4;
  int slice   = bid % 50;
  int jj0  = slice * 8;
  int bat0 = quarter * 4;
  int fbase = dir*200 + quarter*50;            // own gang's flag base
  const float* whhL = whh + (size_t)(layer*2 + dir)*1600*400;
  for (int i = tid; i < 3200; i += 128){        // 32 rows * 100 float4
    int r = i/100, k4 = i%100;
    int g = r>>3, jjr = r&7;
    float4 v = *(const float4*)(whhL + (size_t)(g*400 + jj0 + jjr)*400 + k4*4);
    *(float4*)&Wl[r*404 + k4*4] = v;
  }
  for (int i = tid; i < 4*404; i += 128) hl[i] = 0.f;
  int ks   = (tid>>2)&15;
  int rowg = (tid&3) | ((tid>>6)<<2);
  const float* hb = hl;
  const float* wb = Wl + rowg*4*404;
  int ebl = (tid>>3)&3;                         // local bat 0..3
  int ejj = tid & 7;
  int ebat = bat0 + ebl;
  const float* gbase = G + (size_t)ebat*96*3200 + dir*1600 + jj0 + ejj;
  float* xo = xout + (size_t)ebat*96*800 + dir*400 + jj0 + ejj;
  float c = 0.f;
  float g0=0.f, g1=0.f, g2=0.f, g3=0.f;
  if (tid < 32){
    const float* gp0 = gbase + (size_t)(dir ? 95 : 0)*3200;
    g0 = gp0[0]; g1 = gp0[400]; g2 = gp0[800]; g3 = gp0[1200];
  }
  __syncthreads();
  for (int s = 0; s < 96; s++){
    int t = dir ? 95 - s : s;
    float acc[4][4] = {};
    #pragma unroll
    for (int q = 0; q < 6; ++q){
      int k4 = q*16 + ks;
      float4 h0 = *(const float4*)&hb[0*404 + k4*4];
      float4 h1 = *(const float4*)&hb[1*404 + k4*4];
      float4 h2 = *(const float4*)&hb[2*404 + k4*4];
      float4 h3 = *(const float4*)&hb[3*404 + k4*4];
      float4 w0 = *(const float4*)&wb[0*404 + k4*4];
      float4 w1 = *(const float4*)&wb[1*404 + k4*4];
      float4 w2 = *(const float4*)&wb[2*404 + k4*4];
      float4 w3 = *(const float4*)&wb[3*404 + k4*4];
      #pragma unroll
      for (int bi=0; bi<4; bi++){
        float4 hq = bi==0?h0: bi==1?h1: bi==2?h2: h3;
        #pragma unroll
        for (int ri=0; ri<4; ri++){
          float4 wq = ri==0?w0: ri==1?w1: ri==2?w2: w3;
          acc[bi][ri] = fmaf(hq.x,wq.x, fmaf(hq.y,wq.y,
                        fmaf(hq.z,wq.z, fmaf(hq.w,wq.w, acc[bi][ri]))));
        }
      }
    }
    if (ks < 4){                               // tail k4 = 96..99
      int k4 = 96 + ks;
      float4 h0 = *(const float4*)&hb[0*404 + k4*4];
      float4 h1 = *(const float4*)&hb[1*404 + k4*4];
      float4 h2 = *(const float4*)&hb[2*404 + k4*4];
      float4 h3 = *(const float4*)&hb[3*404 + k4*4];
      float4 w0 = *(const float4*)&wb[0*404 + k4*4];
      float4 w1 = *(const float4*)&wb[1*404 + k4*4];
      float4 w2 = *(const float4*)&wb[2*404 + k4*4];
      float4 w3 = *(const float4*)&wb[3*404 + k4*4];
      #pragma unroll
      for (int bi=0; bi<4; bi++){
        float4 hq = bi==0?h0: bi==1?h1: bi==2?h2: h3;
        #pragma unroll
        for (int ri=0; ri<4; ri++){
          float4 wq = ri==0?w0: ri==1?w1: ri==2?w2: w3;
          acc[bi][ri] = fmaf(hq.x,wq.x, fmaf(hq.y,wq.y,
                        fmaf(hq.z,wq.z, fmaf(hq.w,wq.w, acc[bi][ri]))));
        }
      }
    }
    #pragma unroll
    for (int bi=0; bi<4; bi++)
      #pragma unroll
      for (int ri=0; ri<4; ri++){
        float v = acc[bi][ri];
        v += __shfl_xor(v, 4);
        v += __shfl_xor(v, 8);
        v += __shfl_xor(v, 16);
        v += __shfl_xor(v, 32);
        acc[bi][ri] = v;
      }
    if (ks == 0){
      #pragma unroll
      for (int ri=0; ri<4; ri++)
        #pragma unroll
        for (int bi=0; bi<4; bi++)
          gb[rowg*4+ri][bi] = acc[bi][ri];
    }
    __syncthreads();
    int par = s & 1;
    if (tid < 32){
      float ai = gb[     ejj][ebl] + g0;
      float af = gb[ 8 + ejj][ebl] + g1;
      float ag = gb[16 + ejj][ebl] + g2;
      float ao = gb[24 + ejj][ebl] + g3;
      c = sigf(af)*c + sigf(ai)*tanhf(ag);
      float hv = sigf(ao)*tanhf(c);
      agent_st(&hbufG[((size_t)(par*2 + dir)*16 + ebat)*400 + jj0 + ejj], hv);
      xo[(size_t)t*800] = hv;
    }
    if (s < 95){
      unsigned target = (unsigned)(layer*95 + s + 1);
      __syncthreads();
      if (tid == 0)
        __hip_atomic_store(&flags[bid*16], target, __ATOMIC_RELAXED,
                           __HIP_MEMORY_SCOPE_AGENT);
      if (tid < 32){
        int tn = dir ? 94 - s : s + 1;
        const float* gp = gbase + (size_t)tn*3200;
        g0 = gp[0]; g1 = gp[400]; g2 = gp[800]; g3 = gp[1200];
      }
      if (tid < 50){
        while (__hip_atomic_load(&flags[(fbase + tid)*16], __ATOMIC_RELAXED,
                                 __HIP_MEMORY_SCOPE_AGENT) < target){
          __builtin_amdgcn_s_sleep(1);
        }
      }
      __syncthreads();
      const float* hsrc = hbufG + (size_t)(par*2 + dir)*6400 + bat0*400;
      float hA[4], hB[4], hC[4], hT;
      #pragma unroll
      for (int bat = 0; bat < 4; bat++){
        hA[bat] = agent_ld(hsrc + bat*400 + tid);
        hB[bat] = agent_ld(hsrc + bat*400 + 128 + tid);
        hC[bat] = agent_ld(hsrc + bat*400 + 256 + tid);
      }
      hT = (tid < 64) ? agent_ld(hsrc + (tid>>4)*400 + 384 + (tid&15)) : 0.f;
      #pragma unroll
      for (int bat = 0; bat < 4; bat++){
        hl[bat*404 + tid]       = hA[bat];
        hl[bat*404 + 128 + tid] = hB[bat];
        hl[bat*404 + 256 + tid] = hC[bat];
      }
      if (tid < 64) hl[(tid>>4)*404 + 384 + (tid&15)] = hT;
      __syncthreads();
    }
  }
}

// ---------- log_softmax over last axis of s_arc, write transposed p ----------
__global__ __launch_bounds__(256) void softmax_p(const float* __restrict__ sarc,
                                                 float* __restrict__ p){
  int row  = blockIdx.x*4 + (threadIdx.x >> 6);  // 0..1535  (b,x)
  int lane = threadIdx.x & 63;
  int b = row/96, x = row%96;
  const float* s = sarc + (long)(b*96 + x)*96;
  float v1 = s[lane];
  float v2 = (lane+64 < 96) ? s[lane+64] : -INFINITY;
  float mx = wred_max(fmaxf(v1,v2));
  float sm = wred_sum(__expf(v1-mx) + __expf(v2-mx));
  float lse = mx + __logf(sm);
  float* pr = p + (long)b*9216;
  pr[lane*96 + x] = v1 - lse;
  if (lane+64 < 96) pr[(lane+64)*96 + x] = v2 - lse;
}

// ---------- best_score ----------
__global__ __launch_bounds__(128) void best_kern(const float* __restrict__ p,
                                                 const float* __restrict__ multinomial,
                                                 const int* __restrict__ labels,
                                                 const int* __restrict__ heads,
                                                 float* __restrict__ best){
  int b = blockIdx.x, tid = threadIdx.x;
  float acc = 0.f;
  for (int ti = tid; ti < 95; ti += 128) {
    int y = heads[b*95 + ti];
    int x = ti + 1;
    acc += p[(long)b*9216 + y*96 + x]
         + multinomial[(long)labels[b*96 + y]*64 + labels[b*96 + x]];
  }
  acc = wred_sum(acc);
  __shared__ float tmp[2];
  if ((tid & 63) == 0) tmp[tid >> 6] = acc;
  __syncthreads();
  if (tid == 0) best[b] = tmp[0] + tmp[1];
}

// ---------- Eisner inside, task-parallel + fused phases (r16) ----------
__global__ __launch_bounds__(1024) void inside_kern(const float* __restrict__ p,
                                                    float* __restrict__ part){
  __shared__ float Cp[96][97];
  __shared__ float Ipp[96][97];
  __shared__ float Xp[96][97];
  __shared__ float Pl[96][97];
  int b = blockIdx.x;
  const float* pB = p + (long)b*9216;
  int tid = threadIdx.x;
  for (int idx = tid; idx < 96*97; idx += 1024) {
    int row = idx/97, col = idx%97;
    float d = (row == col) ? 0.f : -1e9f;
    Cp[row][col] = d;
    Xp[row][col] = d;
    Ipp[row][col] = -1e9f;
  }
  for (int idx = tid; idx < 9216; idx += 1024)
    Pl[idx/96][idx%96] = pB[idx];
  __syncthreads();
  int g = tid >> 3, l = tid & 7;   // 128 groups of 8 lanes (same wave)
  for (int w = 1; w < 96; w++){
    int n = 96 - w;
    if (g < n){
      int i = g, j = i + w;
      {
        const float* pa  = &Cp[i][i];
        const float* pb2 = &Cp[j][i+1];
        float vb[12]; float m = -1e30f;
        #pragma unroll
        for (int k = 0; k < 12; k++){
          vb[k] = -1e30f;
          if (k*8 < w){
            int r = l + k*8;
            if (r < w){ float v = pa[r] + pb2[r]; vb[k] = v; m = fmaxf(m, v); }
          }
        }
        m = fmaxf(m, __shfl_xor(m,1));
        m = fmaxf(m, __shfl_xor(m,2));
        m = fmaxf(m, __shfl_xor(m,4));
        float s = 0.f;
        #pragma unroll
        for (int k = 0; k < 12; k++){
          if (k*8 < w) s += __expf(vb[k] - m);
        }
        s += __shfl_xor(s,1); s += __shfl_xor(s,2); s += __shfl_xor(s,4);
        float inc = m + __logf(s);
        if (l == 0){
          Ipp[i][j] = inc + Pl[i][j];
          Ipp[j][i] = inc + Pl[j][i];
        }
      }
      {
        const float* pa1 = &Ipp[i][i+1];
        const float* pb1 = &Xp[j][i+1];
        const float* pa2 = &Xp[i][i];
        const float* pb2 = &Ipp[j][i];
        float v1b[12], v2b[12]; float m1 = -1e30f, m2 = -1e30f;
        #pragma unroll
        for (int k = 0; k < 12; k++){
          v1b[k] = -1e30f; v2b[k] = -1e30f;
          if (k*8 < w){
            int r = l + k*8;
            if (r < w){
              float v1 = pa1[r] + pb1[r]; v1b[k] = v1; m1 = fmaxf(m1, v1);
              float v2 = pa2[r] + pb2[r]; v2b[k] = v2; m2 = fmaxf(m2, v2);
            }
          }
        }
        m1 = fmaxf(m1, __shfl_xor(m1,1));
        m1 = fmaxf(m1, __shfl_xor(m1,2));
        m1 = fmaxf(m1, __shfl_xor(m1,4));
        m2 = fmaxf(m2, __shfl_xor(m2,1));
        m2 = fmaxf(m2, __shfl_xor(m2,2));
        m2 = fmaxf(m2, __shfl_xor(m2,4));
        float s1 = 0.f, s2 = 0.f;
        #pragma unroll
        for (int k = 0; k < 12; k++){
          if (k*8 < w){ s1 += __expf(v1b[k] - m1); s2 += __expf(v2b[k] - m2); }
        }
        s1 += __shfl_xor(s1,1); s1 += __shfl_xor(s1,2); s1 += __shfl_xor(s1,4);
        s2 += __shfl_xor(s2,1); s2 += __shfl_xor(s2,2); s2 += __shfl_xor(s2,4);
        if (l == 0){
          float cr = m1 + __logf(s1);
          float cl = m2 + __logf(s2);
          Cp[i][j] = cr; Xp[j][i] = cr;
          Cp[j][i] = cl; Xp[i][j] = cl;
        }
      }
    }
    __syncthreads();
  }
  if (tid == 0) part[b] = Cp[0][95];
}

// ---------- final mean ----------
__global__ __launch_bounds__(64) void final_kern(const float* __restrict__ part,
                                                 const float* __restrict__ best,
                                                 float* __restrict__ out){
  int lane = threadIdx.x;
  float v = (lane < 16) ? part[lane] - best[lane] : 0.f;
  v = wred_sum(v);
  if (lane == 0) out[0] = v * (1.f/16.f);
}

extern "C" void kernel_launch(void* const* d_in, const int* in_sizes, int n_in,
                              void* d_out, int out_size, void* d_ws, size_t ws_size,
                              hipStream_t stream) {
  const float* emb   = (const float*)d_in[0];
  const float* multi = (const float*)d_in[1];
  const float* wih0  = (const float*)d_in[2];
  const float* wih   = (const float*)d_in[3];
  const float* whh   = (const float*)d_in[4];
  const float* bias  = (const float*)d_in[5];
  const float* mhw   = (const float*)d_in[6];
  const float* mhb   = (const float*)d_in[7];
  const float* mdw   = (const float*)d_in[8];
  const float* mdb   = (const float*)d_in[9];
  const float* biaf  = (const float*)d_in[10];
  const int*   labels= (const int*)d_in[11];
  const int*   heads = (const int*)d_in[12];
  float* out = (float*)d_out;

  float* ws = (float*)d_ws;
  size_t off = 0;
  auto alloc = [&](size_t n){ float* q = ws + off; off += n; return q; };
  float* G    = alloc(1536L*3200);
  float* Gtab = alloc(64L*3200);
  float* xA   = alloc(1536L*800);
  float* xB   = alloc(1536L*800);
  float* WTb  = alloc(500L*500);
  float* arcH = alloc(1536L*500);
  float* arcD = alloc(1536L*500);
  float* tmp  = alloc(1536L*500);
  float* sarc = alloc(16L*96*96);
  float* pbuf = alloc(16L*96*96);
  float* hbufG= alloc(2L*2*16*400);
  unsigned* flags = (unsigned*)alloc(NBLK_LSTM*16);
  float* part = alloc(16);
  float* best = alloc(16);
  (void)ws_size; (void)in_sizes; (void)n_in; (void)out_size;

  hipMemsetAsync(flags, 0, NBLK_LSTM*16*sizeof(unsigned), stream);

  trans_sq<<<(250000+255)/256, 256, 0, stream>>>(biaf, WTb);

  // layer 0: G has only 64 distinct rows -> Gtab (bit-identical k-order)
  // then float4 gather. wih0 rows 0..3199 = [dir][4H] exactly as lstm reads.
  gemm_abt<<<dim3(1,50), 256, 0, stream>>>(emb, wih0, Gtab, bias,
                                           64, 3200, 768, 0,0,0, 0);
  g_gather<<<4800, 256, 0, stream>>>(Gtab, labels, G);
  lstm_grid<<<NBLK_LSTM, 128, 0, stream>>>(G, whh, xA, hbufG, flags, 0);

  const float* xin = xA;
  float* xout = xB;
  for (int l = 1; l < 3; l++) {
    const float* W = wih + (size_t)(l-1)*2*1600*800;
    gemm128<<<dim3(12,25), 256, 0, stream>>>(xin, W, G, bias + l*3200,
                                             1536, 3200, 800, 0);
    lstm_grid<<<NBLK_LSTM, 128, 0, stream>>>(G, whh, xout, hbufG, flags, l);
    xin = xout;
    xout = (l==1) ? xA : xB;
  }
  // xin == xA (l0->xA, l1:xA->xB, l2:xB->xA)
  mlp2_kern<<<dim3(24,8,2), 256, 0, stream>>>(xin, mhw, mhb, mdw, mdb, arcH, arcD);
  dim3 gm(24, 8, 1);
  gemm_abt<<<gm, 256, 0, stream>>>(arcD, WTb, tmp, nullptr, 1536, 500, 500, 0,0,0, 0);
  dim3 gs(2, 2, 16);
  gemm_abt<<<gs, 256, 0, stream>>>(tmp, arcH, sarc, nullptr, 96, 96, 500,
                                   96L*500, 96L*500, 96L*96, 0);
  softmax_p<<<384, 256, 0, stream>>>(sarc, pbuf);
  best_kern<<<16, 128, 0, stream>>>(pbuf, multi, labels, heads, best);
  inside_kern<<<16, 1024, 0, stream>>>(pbuf, part);
  final_kern<<<1, 64, 0, stream>>>(part, best, out);
}

// Round 18
// 1963.009 us; speedup vs baseline: 1.2305x; 1.0038x over previous
//
#include <hip/hip_runtime.h>
#include <cmath>

#define DEV __device__ __forceinline__

// ---------- constants ----------
// B=16, T=96, K=64, D=768, H=400, L=3, M=500
// BT = 1536, 4H = 1600, both dirs = 3200, 2H = 800
// NOTE: the LSTM stack is chaotic (||Whh||~6): recurrence must be fp32-exact
// (fp16 W failed, r2). fp32 k-split reassociation is safe (r8/r12 passed).
// Sync: r6 fence-free agent atomics WIN; r10/r14 REGRESSED (lessons:
// flag-then-load, loads once, FEW pollers). Dot: r13 quarter-split = 388us
// optimum. r15=2164, r16 (inside fusion+mlp2)=2038, r17 (Gtab gather)=1970.
// r18: (1) wave-local drain retry — r14's regression was the 500-poller
// traffic, NOT the drain; barrier #2 only drains wave0's 32 publishes
// (block = 2 waves), replace with wave0 s_waitcnt vmcnt(0) -> 3 barriers.
// Poll structure r13-verbatim (50 pollers, loads once after barrier).
// (2) gemm_abn reads biaffine W untransposed (bit-identical k-order) ->
// trans_sq gone. (3) best_kern fused into inside_kern (Pl already in LDS).

#define NBLK_LSTM 400

DEV float wred_max(float v){ for(int o=32;o;o>>=1) v=fmaxf(v,__shfl_xor(v,o)); return v; }
DEV float wred_sum(float v){ for(int o=32;o;o>>=1) v+=__shfl_xor(v,o); return v; }
DEV float sigf(float x){ return 1.f/(1.f+__expf(-x)); }

DEV float agent_ld(const float* p){
  return __hip_atomic_load(p, __ATOMIC_RELAXED, __HIP_MEMORY_SCOPE_AGENT);
}
DEV void agent_st(float* p, float v){
  __hip_atomic_store(p, v, __ATOMIC_RELAXED, __HIP_MEMORY_SCOPE_AGENT);
}

// ---------- gather G rows from Gtab (layer 0) ----------
__global__ __launch_bounds__(256) void g_gather(const float* __restrict__ Gtab,
                                                const int* __restrict__ labels,
                                                float* __restrict__ G){
  long idx = (long)blockIdx.x*256 + threadIdx.x;   // 1536*800 float4s
  if (idx >= 1536L*800) return;
  int bt = (int)(idx / 800), d4 = (int)(idx - (long)bt*800);
  const float4* src = (const float4*)(Gtab + (size_t)labels[bt]*3200) + d4;
  ((float4*)(G + (size_t)bt*3200))[d4] = *src;
}

// ---------- 64x64 fp32 GEMM (A.B^T) ----------
__global__ __launch_bounds__(256) void gemm_abt(const float* __restrict__ A,
                                                const float* __restrict__ Bm,
                                                float* __restrict__ C,
                                                const float* __restrict__ bias,
                                                int M, int N, int K,
                                                long sA, long sB, long sC, int leaky){
  A  += (long)blockIdx.z * sA;
  Bm += (long)blockIdx.z * sB;
  C  += (long)blockIdx.z * sC;
  __shared__ float As[16][68];
  __shared__ float Bs[16][68];
  int tid = threadIdx.x;
  int tx = tid & 15, ty = tid >> 4;
  int m0 = blockIdx.x * 64, n0 = blockIdx.y * 64;
  int lrow = tid >> 2, lc = (tid & 3) * 4;
  float acc[4][4] = {};
  for (int k0 = 0; k0 < K; k0 += 16) {
    #pragma unroll
    for (int u = 0; u < 4; u++) {
      int k = k0 + lc + u;
      int am = m0 + lrow;
      As[lc+u][lrow] = (am < M && k < K) ? A[(long)am*K + k] : 0.f;
      int bn = n0 + lrow;
      Bs[lc+u][lrow] = (bn < N && k < K) ? Bm[(long)bn*K + k] : 0.f;
    }
    __syncthreads();
    #pragma unroll
    for (int kk = 0; kk < 16; kk++) {
      float a[4], bb[4];
      #pragma unroll
      for (int u=0;u<4;u++){ a[u]=As[kk][ty*4+u]; bb[u]=Bs[kk][tx*4+u]; }
      #pragma unroll
      for (int i=0;i<4;i++)
        #pragma unroll
        for (int j=0;j<4;j++) acc[i][j] = fmaf(a[i], bb[j], acc[i][j]);
    }
    __syncthreads();
  }
  #pragma unroll
  for (int i=0;i<4;i++){
    int m = m0 + ty*4 + i;
    if (m >= M) continue;
    #pragma unroll
    for (int j=0;j<4;j++){
      int n = n0 + tx*4 + j;
      if (n >= N) continue;
      float v = acc[i][j];
      if (bias) v += bias[n];
      if (leaky) v = v > 0.f ? v : 0.1f*v;
      C[(long)m*N + n] = v;
    }
  }
}

// ---------- 64x64 fp32 GEMM, B untransposed: C[m,n]=sum_k A[m,k]*Bn[k*N+n] --
__global__ __launch_bounds__(256) void gemm_abn(const float* __restrict__ A,
                                                const float* __restrict__ Bn,
                                                float* __restrict__ C,
                                                int M, int N, int K){
  __shared__ float As[16][68];
  __shared__ float Bs[16][68];
  int tid = threadIdx.x;
  int tx = tid & 15, ty = tid >> 4;
  int m0 = blockIdx.x * 64, n0 = blockIdx.y * 64;
  int lrow = tid >> 2, lc = (tid & 3) * 4;
  float acc[4][4] = {};
  for (int k0 = 0; k0 < K; k0 += 16) {
    #pragma unroll
    for (int u = 0; u < 4; u++) {
      int k = k0 + lc + u;
      int am = m0 + lrow;
      As[lc+u][lrow] = (am < M && k < K) ? A[(long)am*K + k] : 0.f;
      int bn = n0 + lrow;
      Bs[lc+u][lrow] = (bn < N && k < K) ? Bn[(long)k*N + bn] : 0.f;
    }
    __syncthreads();
    #pragma unroll
    for (int kk = 0; kk < 16; kk++) {
      float a[4], bb[4];
      #pragma unroll
      for (int u=0;u<4;u++){ a[u]=As[kk][ty*4+u]; bb[u]=Bs[kk][tx*4+u]; }
      #pragma unroll
      for (int i=0;i<4;i++)
        #pragma unroll
        for (int j=0;j<4;j++) acc[i][j] = fmaf(a[i], bb[j], acc[i][j]);
    }
    __syncthreads();
  }
  #pragma unroll
  for (int i=0;i<4;i++){
    int m = m0 + ty*4 + i;
    if (m >= M) continue;
    #pragma unroll
    for (int j=0;j<4;j++){
      int n = n0 + tx*4 + j;
      if (n >= N) continue;
      C[(long)m*N + n] = acc[i][j];
    }
  }
}

// ---------- fused arcH+arcD MLP GEMM: z=0 -> arcH, z=1 -> arcD -----------
__global__ __launch_bounds__(256) void mlp2_kern(const float* __restrict__ A,
                                                 const float* __restrict__ Wh,
                                                 const float* __restrict__ bh,
                                                 const float* __restrict__ Wd,
                                                 const float* __restrict__ bd,
                                                 float* __restrict__ Ch,
                                                 float* __restrict__ Cd){
  const float* Bm  = blockIdx.z ? Wd : Wh;
  const float* bias= blockIdx.z ? bd : bh;
  float* C         = blockIdx.z ? Cd : Ch;
  const int M = 1536, N = 500, K = 800;
  __shared__ float As[16][68];
  __shared__ float Bs[16][68];
  int tid = threadIdx.x;
  int tx = tid & 15, ty = tid >> 4;
  int m0 = blockIdx.x * 64, n0 = blockIdx.y * 64;
  int lrow = tid >> 2, lc = (tid & 3) * 4;
  float acc[4][4] = {};
  for (int k0 = 0; k0 < K; k0 += 16) {
    #pragma unroll
    for (int u = 0; u < 4; u++) {
      int k = k0 + lc + u;
      As[lc+u][lrow] = A[(long)(m0+lrow)*K + k];
      int bn = n0 + lrow;
      Bs[lc+u][lrow] = (bn < N) ? Bm[(long)bn*K + k] : 0.f;
    }
    __syncthreads();
    #pragma unroll
    for (int kk = 0; kk < 16; kk++) {
      float a[4], bb[4];
      #pragma unroll
      for (int u=0;u<4;u++){ a[u]=As[kk][ty*4+u]; bb[u]=Bs[kk][tx*4+u]; }
      #pragma unroll
      for (int i=0;i<4;i++)
        #pragma unroll
        for (int j=0;j<4;j++) acc[i][j] = fmaf(a[i], bb[j], acc[i][j]);
    }
    __syncthreads();
  }
  #pragma unroll
  for (int i=0;i<4;i++){
    int m = m0 + ty*4 + i;
    #pragma unroll
    for (int j=0;j<4;j++){
      int n = n0 + tx*4 + j;
      if (n >= N) continue;
      float v = acc[i][j] + bias[n];
      v = v > 0.f ? v : 0.1f*v;
      C[(long)m*N + n] = v;
    }
  }
}

// ---------- 128x128 fp32 GEMM: C[m,n] = sum_k A[m,k]*B[n,k] (+bias,leaky) ----
__global__ __launch_bounds__(256) void gemm128(const float* __restrict__ A,
                                               const float* __restrict__ Bm,
                                               float* __restrict__ C,
                                               const float* __restrict__ bias,
                                               int M, int N, int K, int leaky){
  __shared__ float As[16][132];
  __shared__ float Bs[16][132];
  int tid = threadIdx.x;
  int tx = tid & 15, ty = tid >> 4;
  int m0 = blockIdx.x*128, n0 = blockIdx.y*128;
  int lr = tid >> 1, lq = (tid & 1)*8;
  const float* Arow = A + (size_t)(m0+lr)*K + lq;
  const float* Brow = Bm + (size_t)(n0+lr)*K + lq;
  bool bok = (n0 + lr) < N;
  float acc[8][8] = {};
  for (int k0 = 0; k0 < K; k0 += 16){
    if (k0 + 16 <= K){
      float4 a0 = *(const float4*)(Arow + k0);
      float4 a1 = *(const float4*)(Arow + k0 + 4);
      float4 b0 = {0,0,0,0}, b1 = {0,0,0,0};
      if (bok){ b0 = *(const float4*)(Brow + k0); b1 = *(const float4*)(Brow + k0 + 4); }
      As[lq+0][lr]=a0.x; As[lq+1][lr]=a0.y; As[lq+2][lr]=a0.z; As[lq+3][lr]=a0.w;
      As[lq+4][lr]=a1.x; As[lq+5][lr]=a1.y; As[lq+6][lr]=a1.z; As[lq+7][lr]=a1.w;
      Bs[lq+0][lr]=b0.x; Bs[lq+1][lr]=b0.y; Bs[lq+2][lr]=b0.z; Bs[lq+3][lr]=b0.w;
      Bs[lq+4][lr]=b1.x; Bs[lq+5][lr]=b1.y; Bs[lq+6][lr]=b1.z; Bs[lq+7][lr]=b1.w;
    } else {
      #pragma unroll
      for (int u = 0; u < 8; u++){
        int k = k0 + lq + u;
        As[lq+u][lr] = (k < K) ? Arow[k0+u] : 0.f;
        Bs[lq+u][lr] = (bok && k < K) ? Brow[k0+u] : 0.f;
      }
    }
    __syncthreads();
    #pragma unroll
    for (int kk = 0; kk < 16; kk++){
      float4 a0 = *(const float4*)&As[kk][ty*8];
      float4 a1 = *(const float4*)&As[kk][ty*8+4];
      float4 b0 = *(const float4*)&Bs[kk][tx*8];
      float4 b1 = *(const float4*)&Bs[kk][tx*8+4];
      float av[8] = {a0.x,a0.y,a0.z,a0.w,a1.x,a1.y,a1.z,a1.w};
      float bv[8] = {b0.x,b0.y,b0.z,b0.w,b1.x,b1.y,b1.z,b1.w};
      #pragma unroll
      for (int i=0;i<8;i++)
        #pragma unroll
        for (int j=0;j<8;j++) acc[i][j] = fmaf(av[i], bv[j], acc[i][j]);
    }
    __syncthreads();
  }
  bool full = (n0 + 128 <= N);
  #pragma unroll
  for (int i = 0; i < 8; i++){
    int m = m0 + ty*8 + i;
    float* Crow = C + (size_t)m*N;
    if (full){
      float4 v0, v1;
      float* p0 = &v0.x; float* p1 = &v1.x;
      #pragma unroll
      for (int j = 0; j < 4; j++){
        int n = n0 + tx*8 + j;
        float v = acc[i][j];
        if (bias) v += bias[n];
        if (leaky) v = v > 0.f ? v : 0.1f*v;
        p0[j] = v;
      }
      #pragma unroll
      for (int j = 4; j < 8; j++){
        int n = n0 + tx*8 + j;
        float v = acc[i][j];
        if (bias) v += bias[n];
        if (leaky) v = v > 0.f ? v : 0.1f*v;
        p1[j-4] = v;
      }
      *(float4*)(Crow + n0 + tx*8)     = v0;
      *(float4*)(Crow + n0 + tx*8 + 4) = v1;
    } else {
      #pragma unroll
      for (int j = 0; j < 8; j++){
        int n = n0 + tx*8 + j;
        if (n < N){
          float v = acc[i][j];
          if (bias) v += bias[n];
          if (leaky) v = v > 0.f ? v : 0.1f*v;
          Crow[n] = v;
        }
      }
    }
  }
}

// ---------- weight-stationary grid-synced LSTM (one layer, 96 steps) --------
// r13 decomposition; r18 sync: 3 barriers/step. Block = 2 waves; publishers
// are wave0 lanes 0-31, so wave0 s_waitcnt vmcnt(0) + tid0 flag replaces
// the block drain barrier. Poll structure r13-verbatim (tid<50 pollers,
// loads issued once after a barrier). xo + G-prefetch moved after flag.
__global__ __launch_bounds__(128) void lstm_grid(const float* __restrict__ G,
                                                 const float* __restrict__ whh,
                                                 float* __restrict__ xout,
                                                 float* __restrict__ hbufG,
                                                 unsigned* __restrict__ flags,
                                                 int layer){
  __shared__ float Wl[32*404];    // 32 rows x 400 (+4 pad) = 51.7KB
  __shared__ float hl[4*404];     // 4 bat x 400 (+4 pad)   = 6.5KB
  __shared__ float gb[32][5];     // gate dots [row][local bat]
  int tid = threadIdx.x;
  int bid = blockIdx.x;
  int dir     = bid / 200;
  int quarter = (bid / 50) % 4;
  int slice   = bid % 50;
  int jj0  = slice * 8;
  int bat0 = quarter * 4;
  int fbase = dir*200 + quarter*50;            // own gang's flag base
  const float* whhL = whh + (size_t)(layer*2 + dir)*1600*400;
  for (int i = tid; i < 3200; i += 128){        // 32 rows * 100 float4
    int r = i/100, k4 = i%100;
    int g = r>>3, jjr = r&7;
    float4 v = *(const float4*)(whhL + (size_t)(g*400 + jj0 + jjr)*400 + k4*4);
    *(float4*)&Wl[r*404 + k4*4] = v;
  }
  for (int i = tid; i < 4*404; i += 128) hl[i] = 0.f;
  int ks   = (tid>>2)&15;
  int rowg = (tid&3) | ((tid>>6)<<2);
  const float* hb = hl;
  const float* wb = Wl + rowg*4*404;
  int ebl = (tid>>3)&3;                         // local bat 0..3
  int ejj = tid & 7;
  int ebat = bat0 + ebl;
  const float* gbase = G + (size_t)ebat*96*3200 + dir*1600 + jj0 + ejj;
  float* xo = xout + (size_t)ebat*96*800 + dir*400 + jj0 + ejj;
  float c = 0.f;
  float g0=0.f, g1=0.f, g2=0.f, g3=0.f;
  if (tid < 32){
    const float* gp0 = gbase + (size_t)(dir ? 95 : 0)*3200;
    g0 = gp0[0]; g1 = gp0[400]; g2 = gp0[800]; g3 = gp0[1200];
  }
  __syncthreads();
  for (int s = 0; s < 96; s++){
    int t = dir ? 95 - s : s;
    float acc[4][4] = {};
    #pragma unroll
    for (int q = 0; q < 6; ++q){
      int k4 = q*16 + ks;
      float4 h0 = *(const float4*)&hb[0*404 + k4*4];
      float4 h1 = *(const float4*)&hb[1*404 + k4*4];
      float4 h2 = *(const float4*)&hb[2*404 + k4*4];
      float4 h3 = *(const float4*)&hb[3*404 + k4*4];
      float4 w0 = *(const float4*)&wb[0*404 + k4*4];
      float4 w1 = *(const float4*)&wb[1*404 + k4*4];
      float4 w2 = *(const float4*)&wb[2*404 + k4*4];
      float4 w3 = *(const float4*)&wb[3*404 + k4*4];
      #pragma unroll
      for (int bi=0; bi<4; bi++){
        float4 hq = bi==0?h0: bi==1?h1: bi==2?h2: h3;
        #pragma unroll
        for (int ri=0; ri<4; ri++){
          float4 wq = ri==0?w0: ri==1?w1: ri==2?w2: w3;
          acc[bi][ri] = fmaf(hq.x,wq.x, fmaf(hq.y,wq.y,
                        fmaf(hq.z,wq.z, fmaf(hq.w,wq.w, acc[bi][ri]))));
        }
      }
    }
    if (ks < 4){                               // tail k4 = 96..99
      int k4 = 96 + ks;
      float4 h0 = *(const float4*)&hb[0*404 + k4*4];
      float4 h1 = *(const float4*)&hb[1*404 + k4*4];
      float4 h2 = *(const float4*)&hb[2*404 + k4*4];
      float4 h3 = *(const float4*)&hb[3*404 + k4*4];
      float4 w0 = *(const float4*)&wb[0*404 + k4*4];
      float4 w1 = *(const float4*)&wb[1*404 + k4*4];
      float4 w2 = *(const float4*)&wb[2*404 + k4*4];
      float4 w3 = *(const float4*)&wb[3*404 + k4*4];
      #pragma unroll
      for (int bi=0; bi<4; bi++){
        float4 hq = bi==0?h0: bi==1?h1: bi==2?h2: h3;
        #pragma unroll
        for (int ri=0; ri<4; ri++){
          float4 wq = ri==0?w0: ri==1?w1: ri==2?w2: w3;
          acc[bi][ri] = fmaf(hq.x,wq.x, fmaf(hq.y,wq.y,
                        fmaf(hq.z,wq.z, fmaf(hq.w,wq.w, acc[bi][ri]))));
        }
      }
    }
    #pragma unroll
    for (int bi=0; bi<4; bi++)
      #pragma unroll
      for (int ri=0; ri<4; ri++){
        float v = acc[bi][ri];
        v += __shfl_xor(v, 4);
        v += __shfl_xor(v, 8);
        v += __shfl_xor(v, 16);
        v += __shfl_xor(v, 32);
        acc[bi][ri] = v;
      }
    if (ks == 0){
      #pragma unroll
      for (int ri=0; ri<4; ri++)
        #pragma unroll
        for (int bi=0; bi<4; bi++)
          gb[rowg*4+ri][bi] = acc[bi][ri];
    }
    __syncthreads();                 // (A) gb ready; hl reads done
    int par = s & 1;
    float hv = 0.f;
    if (tid < 32){                   // epilogue: wave0 lanes 0-31
      float ai = gb[     ejj][ebl] + g0;
      float af = gb[ 8 + ejj][ebl] + g1;
      float ag = gb[16 + ejj][ebl] + g2;
      float ao = gb[24 + ejj][ebl] + g3;
      c = sigf(af)*c + sigf(ai)*tanhf(ag);
      hv = sigf(ao)*tanhf(c);
      if (s < 95)
        agent_st(&hbufG[((size_t)(par*2 + dir)*16 + ebat)*400 + jj0 + ejj], hv);
    }
    if (s < 95){
      unsigned target = (unsigned)(layer*95 + s + 1);
      if (tid < 64){                 // wave0: drain own publishes, raise flag
        asm volatile("s_waitcnt vmcnt(0)" ::: "memory");
        if (tid == 0)
          __hip_atomic_store(&flags[bid*16], target, __ATOMIC_RELAXED,
                             __HIP_MEMORY_SCOPE_AGENT);
      }
      if (tid < 32){                 // after flag: xo + next-step G prefetch
        xo[(size_t)t*800] = hv;
        int tn = dir ? 94 - s : s + 1;
        const float* gp = gbase + (size_t)tn*3200;
        g0 = gp[0]; g1 = gp[400]; g2 = gp[800]; g3 = gp[1200];
      }
      if (tid < 50){                 // wait on own (dir,quarter) gang only
        while (__hip_atomic_load(&flags[(fbase + tid)*16], __ATOMIC_RELAXED,
                                 __HIP_MEMORY_SCOPE_AGENT) < target){
          __builtin_amdgcn_s_sleep(1);
        }
      }
      __syncthreads();               // (#3) flags passed -> loads may start
      const float* hsrc = hbufG + (size_t)(par*2 + dir)*6400 + bat0*400;
      float hA[4], hB[4], hC[4], hT;
      #pragma unroll
      for (int bat = 0; bat < 4; bat++){
        hA[bat] = agent_ld(hsrc + bat*400 + tid);
        hB[bat] = agent_ld(hsrc + bat*400 + 128 + tid);
        hC[bat] = agent_ld(hsrc + bat*400 + 256 + tid);
      }
      hT = (tid < 64) ? agent_ld(hsrc + (tid>>4)*400 + 384 + (tid&15)) : 0.f;
      #pragma unroll
      for (int bat = 0; bat < 4; bat++){
        hl[bat*404 + tid]       = hA[bat];
        hl[bat*404 + 128 + tid] = hB[bat];
        hl[bat*404 + 256 + tid] = hC[bat];
      }
      if (tid < 64) hl[(tid>>4)*404 + 384 + (tid&15)] = hT;
      __syncthreads();               // (B) hl ready for next dot
    } else {
      if (tid < 32) xo[(size_t)t*800] = hv;
    }
  }
}

// ---------- log_softmax over last axis of s_arc, write transposed p ----------
__global__ __launch_bounds__(256) void softmax_p(const float* __restrict__ sarc,
                                                 float* __restrict__ p){
  int row  = blockIdx.x*4 + (threadIdx.x >> 6);  // 0..1535  (b,x)
  int lane = threadIdx.x & 63;
  int b = row/96, x = row%96;
  const float* s = sarc + (long)(b*96 + x)*96;
  float v1 = s[lane];
  float v2 = (lane+64 < 96) ? s[lane+64] : -INFINITY;
  float mx = wred_max(fmaxf(v1,v2));
  float sm = wred_sum(__expf(v1-mx) + __expf(v2-mx));
  float lse = mx + __logf(sm);
  float* pr = p + (long)b*9216;
  pr[lane*96 + x] = v1 - lse;
  if (lane+64 < 96) pr[(lane+64)*96 + x] = v2 - lse;
}

// ---------- Eisner inside + fused best-score (r16 + r18) ----------
__global__ __launch_bounds__(1024) void inside_kern(const float* __restrict__ p,
                                                    const float* __restrict__ multinomial,
                                                    const int* __restrict__ labels,
                                                    const int* __restrict__ heads,
                                                    float* __restrict__ part,
                                                    float* __restrict__ best){
  __shared__ float Cp[96][97];
  __shared__ float Ipp[96][97];
  __shared__ float Xp[96][97];
  __shared__ float Pl[96][97];
  __shared__ float bpart[16];
  int b = blockIdx.x;
  const float* pB = p + (long)b*9216;
  int tid = threadIdx.x;
  for (int idx = tid; idx < 96*97; idx += 1024) {
    int row = idx/97, col = idx%97;
    float d = (row == col) ? 0.f : -1e9f;
    Cp[row][col] = d;
    Xp[row][col] = d;
    Ipp[row][col] = -1e9f;
  }
  for (int idx = tid; idx < 9216; idx += 1024)
    Pl[idx/96][idx%96] = pB[idx];
  __syncthreads();
  // fused best-score (reads Pl, 95 gather terms)
  {
    float accb = 0.f;
    if (tid < 95){
      int y = heads[b*95 + tid];
      int x = tid + 1;
      accb = Pl[y][x]
           + multinomial[(long)labels[b*96 + y]*64 + labels[b*96 + x]];
    }
    accb = wred_sum(accb);
    if ((tid & 63) == 0) bpart[tid >> 6] = accb;
    __syncthreads();
    if (tid == 0) best[b] = bpart[0] + bpart[1];
  }
  int g = tid >> 3, l = tid & 7;   // 128 groups of 8 lanes (same wave)
  for (int w = 1; w < 96; w++){
    int n = 96 - w;
    if (g < n){
      int i = g, j = i + w;
      {
        const float* pa  = &Cp[i][i];
        const float* pb2 = &Cp[j][i+1];
        float vb[12]; float m = -1e30f;
        #pragma unroll
        for (int k = 0; k < 12; k++){
          vb[k] = -1e30f;
          if (k*8 < w){
            int r = l + k*8;
            if (r < w){ float v = pa[r] + pb2[r]; vb[k] = v; m = fmaxf(m, v); }
          }
        }
        m = fmaxf(m, __shfl_xor(m,1));
        m = fmaxf(m, __shfl_xor(m,2));
        m = fmaxf(m, __shfl_xor(m,4));
        float s = 0.f;
        #pragma unroll
        for (int k = 0; k < 12; k++){
          if (k*8 < w) s += __expf(vb[k] - m);
        }
        s += __shfl_xor(s,1); s += __shfl_xor(s,2); s += __shfl_xor(s,4);
        float inc = m + __logf(s);
        if (l == 0){
          Ipp[i][j] = inc + Pl[i][j];
          Ipp[j][i] = inc + Pl[j][i];
        }
      }
      {
        const float* pa1 = &Ipp[i][i+1];
        const float* pb1 = &Xp[j][i+1];
        const float* pa2 = &Xp[i][i];
        const float* pb2 = &Ipp[j][i];
        float v1b[12], v2b[12]; float m1 = -1e30f, m2 = -1e30f;
        #pragma unroll
        for (int k = 0; k < 12; k++){
          v1b[k] = -1e30f; v2b[k] = -1e30f;
          if (k*8 < w){
            int r = l + k*8;
            if (r < w){
              float v1 = pa1[r] + pb1[r]; v1b[k] = v1; m1 = fmaxf(m1, v1);
              float v2 = pa2[r] + pb2[r]; v2b[k] = v2; m2 = fmaxf(m2, v2);
            }
          }
        }
        m1 = fmaxf(m1, __shfl_xor(m1,1));
        m1 = fmaxf(m1, __shfl_xor(m1,2));
        m1 = fmaxf(m1, __shfl_xor(m1,4));
        m2 = fmaxf(m2, __shfl_xor(m2,1));
        m2 = fmaxf(m2, __shfl_xor(m2,2));
        m2 = fmaxf(m2, __shfl_xor(m2,4));
        float s1 = 0.f, s2 = 0.f;
        #pragma unroll
        for (int k = 0; k < 12; k++){
          if (k*8 < w){ s1 += __expf(v1b[k] - m1); s2 += __expf(v2b[k] - m2); }
        }
        s1 += __shfl_xor(s1,1); s1 += __shfl_xor(s1,2); s1 += __shfl_xor(s1,4);
        s2 += __shfl_xor(s2,1); s2 += __shfl_xor(s2,2); s2 += __shfl_xor(s2,4);
        if (l == 0){
          float cr = m1 + __logf(s1);
          float cl = m2 + __logf(s2);
          Cp[i][j] = cr; Xp[j][i] = cr;
          Cp[j][i] = cl; Xp[i][j] = cl;
        }
      }
    }
    __syncthreads();
  }
  if (tid == 0) part[b] = Cp[0][95];
}

// ---------- final mean ----------
__global__ __launch_bounds__(64) void final_kern(const float* __restrict__ part,
                                                 const float* __restrict__ best,
                                                 float* __restrict__ out){
  int lane = threadIdx.x;
  float v = (lane < 16) ? part[lane] - best[lane] : 0.f;
  v = wred_sum(v);
  if (lane == 0) out[0] = v * (1.f/16.f);
}

extern "C" void kernel_launch(void* const* d_in, const int* in_sizes, int n_in,
                              void* d_out, int out_size, void* d_ws, size_t ws_size,
                              hipStream_t stream) {
  const float* emb   = (const float*)d_in[0];
  const float* multi = (const float*)d_in[1];
  const float* wih0  = (const float*)d_in[2];
  const float* wih   = (const float*)d_in[3];
  const float* whh   = (const float*)d_in[4];
  const float* bias  = (const float*)d_in[5];
  const float* mhw   = (const float*)d_in[6];
  const float* mhb   = (const float*)d_in[7];
  const float* mdw   = (const float*)d_in[8];
  const float* mdb   = (const float*)d_in[9];
  const float* biaf  = (const float*)d_in[10];
  const int*   labels= (const int*)d_in[11];
  const int*   heads = (const int*)d_in[12];
  float* out = (float*)d_out;

  float* ws = (float*)d_ws;
  size_t off = 0;
  auto alloc = [&](size_t n){ float* q = ws + off; off += n; return q; };
  float* G    = alloc(1536L*3200);
  float* Gtab = alloc(64L*3200);
  float* xA   = alloc(1536L*800);
  float* xB   = alloc(1536L*800);
  float* arcH = alloc(1536L*500);
  float* arcD = alloc(1536L*500);
  float* tmp  = alloc(1536L*500);
  float* sarc = alloc(16L*96*96);
  float* pbuf = alloc(16L*96*96);
  float* hbufG= alloc(2L*2*16*400);
  unsigned* flags = (unsigned*)alloc(NBLK_LSTM*16);
  float* part = alloc(16);
  float* best = alloc(16);
  (void)ws_size; (void)in_sizes; (void)n_in; (void)out_size;

  hipMemsetAsync(flags, 0, NBLK_LSTM*16*sizeof(unsigned), stream);

  // layer 0: G has only 64 distinct rows -> Gtab (bit-identical k-order)
  gemm_abt<<<dim3(1,50), 256, 0, stream>>>(emb, wih0, Gtab, bias,
                                           64, 3200, 768, 0,0,0, 0);
  g_gather<<<4800, 256, 0, stream>>>(Gtab, labels, G);
  lstm_grid<<<NBLK_LSTM, 128, 0, stream>>>(G, whh, xA, hbufG, flags, 0);

  const float* xin = xA;
  float* xout = xB;
  for (int l = 1; l < 3; l++) {
    const float* W = wih + (size_t)(l-1)*2*1600*800;
    gemm128<<<dim3(12,25), 256, 0, stream>>>(xin, W, G, bias + l*3200,
                                             1536, 3200, 800, 0);
    lstm_grid<<<NBLK_LSTM, 128, 0, stream>>>(G, whh, xout, hbufG, flags, l);
    xin = xout;
    xout = (l==1) ? xA : xB;
  }
  // xin == xA (l0->xA, l1:xA->xB, l2:xB->xA)
  mlp2_kern<<<dim3(24,8,2), 256, 0, stream>>>(xin, mhw, mhb, mdw, mdb, arcH, arcD);
  gemm_abn<<<dim3(24,8), 256, 0, stream>>>(arcD, biaf, tmp, 1536, 500, 500);
  dim3 gs(2, 2, 16);
  gemm_abt<<<gs, 256, 0, stream>>>(tmp, arcH, sarc, nullptr, 96, 96, 500,
                                   96L*500, 96L*500, 96L*96, 0);
  softmax_p<<<384, 256, 0, stream>>>(sarc, pbuf);
  inside_kern<<<16, 1024, 0, stream>>>(pbuf, multi, labels, heads, part, best);
  final_kern<<<1, 64, 0, stream>>>(part, best, out);
}